// Round 7
// baseline (316.052 us; speedup 1.0000x reference)
//
#include <hip/hip_runtime.h>
#include <hip/hip_bf16.h>
#include <cmath>

typedef __bf16 bf16;
typedef __bf16 bf16x4 __attribute__((ext_vector_type(4)));
typedef __bf16 bf16x8 __attribute__((ext_vector_type(8)));
typedef float f32x4 __attribute__((ext_vector_type(4)));

#define BB 2
#define SS 2048
#define DD 1024
#define HH 16
#define WW 16
#define HDD 64
#define DFFD 4096
#define NTOK (BB*SS)

// gelu(x) = x * sigmoid(2*sqrt(2/pi)*(x+0.044715x^3))  == tanh-approx gelu
__device__ __forceinline__ float gelu_f(float x) {
    const float k = 1.5957691216057308f;  // 2*sqrt(2/pi)
    float u = k * (x + 0.044715f * x * x * x);
    return x / (1.0f + __expf(-u));
}

// ---- async global->LDS 16B/lane. LDS dest = wave-uniform base; HW adds lane*16. ----
__device__ __forceinline__ void glds16(const bf16* g, const bf16* l) {
    __builtin_amdgcn_global_load_lds(
        (const __attribute__((address_space(1))) void*)(uintptr_t)(const void*)g,
        (__attribute__((address_space(3))) void*)(unsigned)(uintptr_t)(const void*)l,
        16, 0, 0);
}

// ---------------- fp32 -> bf16 convert, 8 elems/thread ----------------
__global__ __launch_bounds__(256) void conv_kernel(
    const float* __restrict__ src, bf16* __restrict__ dst, int n8)
{
    int i = blockIdx.x * 256 + threadIdx.x;
    if (i >= n8) return;
    f32x4 a = *(const f32x4*)(src + (size_t)i * 8);
    f32x4 b = *(const f32x4*)(src + (size_t)i * 8 + 4);
    bf16x8 v;
#pragma unroll
    for (int j = 0; j < 4; j++) { v[j] = (bf16)a[j]; v[4 + j] = (bf16)b[j]; }
    *(bf16x8*)(dst + (size_t)i * 8) = v;
}

// ---------------- fused LayerNorm: fp32 row -> bf16 row, one block/row ----------------
__global__ __launch_bounds__(256) void ln_kernel(
    const float* __restrict__ x, const float* __restrict__ g, const float* __restrict__ b,
    bf16* __restrict__ out)
{
    const int row = blockIdx.x, t = threadIdx.x;
    f32x4 v = *(const f32x4*)(x + (size_t)row * DD + t * 4);
    float s  = v[0] + v[1] + v[2] + v[3];
    float s2 = v[0]*v[0] + v[1]*v[1] + v[2]*v[2] + v[3]*v[3];
#pragma unroll
    for (int off = 32; off >= 1; off >>= 1) {
        s  += __shfl_xor(s,  off, 64);
        s2 += __shfl_xor(s2, off, 64);
    }
    __shared__ float red[8];
    const int wave = t >> 6;
    if ((t & 63) == 0) { red[wave] = s; red[4 + wave] = s2; }
    __syncthreads();
    float ts  = red[0] + red[1] + red[2] + red[3];
    float ts2 = red[4] + red[5] + red[6] + red[7];
    float mean = ts * (1.0f / DD);
    float var  = ts2 * (1.0f / DD) - mean * mean;
    float rstd = rsqrtf(var + 1e-5f);
    f32x4 gv = *(const f32x4*)(g + t * 4);
    f32x4 bv = *(const f32x4*)(b + t * 4);
    bf16x4 o;
#pragma unroll
    for (int i = 0; i < 4; i++) o[i] = (bf16)((v[i] - mean) * rstd * gv[i] + bv[i]);
    *(bf16x4*)(out + (size_t)row * DD + t * 4) = o;
}

// ---------------- bf16 MFMA GEMM, 2-phase double-buffered glds prefetch ----------------
// C[M,N] = A[M,K] @ W[N,K]^T + bias.  (T3-minimum-2phase; the winning structure:
// 128x128 tile, 16/24/32 KB LDS -> 4+ blocks/CU co-resident. m114 mechanism: the
// co-resident blocks' phases interleave across the CU, overlapping LDS/MFMA/HBM
// pipes without any explicit schedule. Verified this session: 2ph-4blk = 72.6 us
// on MLP1 vs 82-86 us for all three 1-blk/CU 8-phase variants.)
// TM=128 (waves 2x2, 4x4 frags) or 64 (1x4, 4x2). BN=128, BK=32, 256 thr.
// RESID: 2=add fp32 resid (may alias fp32 Cout: same elem, same thread,
// read-before-write). 3=split-K over gridDim.z, unsafeAtomicAdd into pre-primed
// fp32 Cout, bias at z==0 only. ACT: 1=gelu. OUTF32: 1=fp32 out, 0=bf16.
template<int TM, int ACT, int RESID, int OUTF32>
__global__ __launch_bounds__(256) void gemm_glds(
    const bf16* __restrict__ A, const bf16* __restrict__ Bw,
    const float* __restrict__ bias,
    const float* resid, void* __restrict__ Cout, int N, int K)
{
    constexpr int MI = 4;
    constexpr int NJ = (TM == 128) ? 4 : 2;
    __shared__ __align__(16) bf16 As[2 * TM * 32];
    __shared__ __align__(16) bf16 Bs[2 * 128 * 32];
    const int t = threadIdx.x;
    const int m0 = blockIdx.y * TM, n0 = blockIdx.x * 128;
    const int lane = t & 63, w = t >> 6;
    const int wm = (TM == 128) ? (w & 1) * 64 : 0;
    const int wn = (TM == 128) ? (w >> 1) * 64 : w * 32;
    const int quad = lane >> 4, l16 = lane & 15;
    const int srow = t >> 2, scol = (t & 3) * 8;   // 4 lanes/row, 8 bf16 (16 B) each

    const bf16* Ag = A  + (size_t)(m0 + srow) * K + scol;
    const bf16* Bg = Bw + (size_t)(n0 + srow) * K + scol;

    int k_lo = 0, k_hi = K;
    if (RESID == 3) {                 // split-K: this block handles one K-slice
        const int ks = K / gridDim.z;
        k_lo = blockIdx.z * ks;
        k_hi = k_lo + ks;
    }

    auto stage = [&](int buf, int k0) {
        const bf16* AsW = As + buf * (TM * 32) + w * 512;
        const bf16* BsW = Bs + buf * (128 * 32) + w * 512;
        glds16(Ag + k0, AsW);
        if (TM == 128) glds16(Ag + (size_t)64 * K + k0, AsW + 2048);
        glds16(Bg + k0, BsW);
        glds16(Bg + (size_t)64 * K + k0, BsW + 2048);
    };

    const f32x4 zero = {0.f, 0.f, 0.f, 0.f};
    f32x4 acc[MI][NJ];
#pragma unroll
    for (int i = 0; i < MI; i++)
#pragma unroll
        for (int j = 0; j < NJ; j++) acc[i][j] = zero;

    const int nsteps = (k_hi - k_lo) >> 5;
    stage(0, k_lo);
    __syncthreads();                           // drains vmcnt -> buf0 visible

    for (int step = 0; step < nsteps; ++step) {
        const int cur = step & 1;
        if (step + 1 < nsteps)
            stage(cur ^ 1, k_lo + ((step + 1) << 5));   // prefetch next tile
        const bf16* Ab = As + cur * (TM * 32);
        const bf16* Bb = Bs + cur * (128 * 32);
        bf16x8 af[MI], bfr[NJ];
#pragma unroll
        for (int i = 0; i < MI; i++)
            af[i] = *(const bf16x8*)(Ab + (wm + i * 16 + l16) * 32 + quad * 8);
#pragma unroll
        for (int j = 0; j < NJ; j++)
            bfr[j] = *(const bf16x8*)(Bb + (wn + j * 16 + l16) * 32 + quad * 8);
#pragma unroll
        for (int i = 0; i < MI; i++)
#pragma unroll
            for (int j = 0; j < NJ; j++)
                acc[i][j] = __builtin_amdgcn_mfma_f32_16x16x32_bf16(af[i], bfr[j], acc[i][j], 0, 0, 0);
        __syncthreads();   // implicit vmcnt(0)+lgkmcnt(0): prefetch landed, reads done
    }

#pragma unroll
    for (int i = 0; i < MI; i++) {
#pragma unroll
        for (int j = 0; j < NJ; j++) {
            int col = n0 + wn + j * 16 + l16;
            float bv = bias[col];
            if (RESID == 3 && blockIdx.z != 0) bv = 0.0f;
#pragma unroll
            for (int r = 0; r < 4; r++) {
                int row = m0 + wm + i * 16 + quad * 4 + r;
                float val = acc[i][j][r] + bv;
                if (ACT == 1) val = gelu_f(val);
                size_t idx = (size_t)row * N + col;
                if (RESID == 2) val += resid[idx];
                if (RESID == 3) {
                    unsafeAtomicAdd(&((float*)Cout)[idx], val);   // HW global_atomic_add_f32
                } else if (OUTF32) {
                    ((float*)Cout)[idx] = val;
                } else {
                    ((bf16*)Cout)[idx] = (bf16)val;
                }
            }
        }
    }
}

// ---------------- Sliding-window causal attention, MFMA-tiled ----------------
// One wave per (b, h, 16-query block); window W=16 -> two 16-key tiles.
// QK^T: 4 MFMAs, A/B frags direct from global. Softmax: 16-lane butterfly.
// P via 1KB wave-private LDS; V staged per-wave via glds16, consumed transposed.
__global__ __launch_bounds__(256) void attn_kernel(
    const bf16* __restrict__ qkv, bf16* __restrict__ o)
{
    __shared__ __align__(16) bf16 Vlds[4][32 * 64];
    __shared__ __align__(16) bf16 Plds[4][16 * 32];
    const int t = threadIdx.x;
    const int w = t >> 6, lane = t & 63;
    const int quad = lane >> 4, l16 = lane & 15;
    const int gw = blockIdx.x * 4 + w;
    const int qb = gw & 127;
    const int h  = (gw >> 7) & (HH - 1);
    const int b  = gw >> 11;
    const int q0 = qb << 4;
    const size_t rs = 3 * DD;
    const bf16* Qb = qkv + (size_t)b * SS * rs + h * HDD;
    const bf16* Kb = Qb + DD;
    const bf16* Vb = Qb + 2 * DD;
    bf16* Vw = Vlds[w];
    bf16* Pw = Plds[w];

    {
        const int sub = lane >> 3;
        const int dc  = (lane & 7) * 8;
#pragma unroll
        for (int c = 0; c < 4; c++) {
            int key = q0 - 16 + c * 8 + sub;
            if (key < 0) key = 0;
            glds16(Vb + (size_t)key * rs + dc, Vw + c * 512);
        }
    }

    const int qrow = q0 + l16;
    int kr0 = q0 - 16 + l16; if (kr0 < 0) kr0 = 0;
    bf16x8 qf0  = *(const bf16x8*)(Qb + (size_t)qrow * rs + quad * 8);
    bf16x8 qf1  = *(const bf16x8*)(Qb + (size_t)qrow * rs + 32 + quad * 8);
    bf16x8 kf0a = *(const bf16x8*)(Kb + (size_t)kr0  * rs + quad * 8);
    bf16x8 kf0b = *(const bf16x8*)(Kb + (size_t)kr0  * rs + 32 + quad * 8);
    bf16x8 kf1a = *(const bf16x8*)(Kb + (size_t)qrow * rs + quad * 8);
    bf16x8 kf1b = *(const bf16x8*)(Kb + (size_t)qrow * rs + 32 + quad * 8);

    const f32x4 zero = {0.f, 0.f, 0.f, 0.f};
    f32x4 acc0 = __builtin_amdgcn_mfma_f32_16x16x32_bf16(qf0, kf0a, zero, 0, 0, 0);
    acc0 = __builtin_amdgcn_mfma_f32_16x16x32_bf16(qf1, kf0b, acc0, 0, 0, 0);
    f32x4 acc1 = __builtin_amdgcn_mfma_f32_16x16x32_bf16(qf0, kf1a, zero, 0, 0, 0);
    acc1 = __builtin_amdgcn_mfma_f32_16x16x32_bf16(qf1, kf1b, acc1, 0, 0, 0);

    float rl[4];
#pragma unroll
    for (int r = 0; r < 4; r++) {
        const int row = quad * 4 + r;
        float s0 = (l16 > row && q0 - 16 + l16 >= 0) ? acc0[r] * 0.125f : -1e30f;
        float s1 = (l16 <= row)                      ? acc1[r] * 0.125f : -1e30f;
        float m = fmaxf(s0, s1);
        m = fmaxf(m, __shfl_xor(m, 1, 64));
        m = fmaxf(m, __shfl_xor(m, 2, 64));
        m = fmaxf(m, __shfl_xor(m, 4, 64));
        m = fmaxf(m, __shfl_xor(m, 8, 64));
        float e0 = __expf(s0 - m), e1 = __expf(s1 - m);
        float sum = e0 + e1;
        sum += __shfl_xor(sum, 1, 64);
        sum += __shfl_xor(sum, 2, 64);
        sum += __shfl_xor(sum, 4, 64);
        sum += __shfl_xor(sum, 8, 64);
        rl[r] = 1.0f / sum;
        Pw[row * 32 + l16]      = (bf16)e0;
        Pw[row * 32 + 16 + l16] = (bf16)e1;
    }

    asm volatile("s_waitcnt vmcnt(0)" ::: "memory");
    bf16x8 pf = *(const bf16x8*)(Pw + l16 * 32 + quad * 8);
#pragma unroll
    for (int dt = 0; dt < 4; dt++) {
        bf16x8 vf;
#pragma unroll
        for (int jj = 0; jj < 8; jj++)
            vf[jj] = Vw[(quad * 8 + jj) * 64 + dt * 16 + l16];
        f32x4 ov = __builtin_amdgcn_mfma_f32_16x16x32_bf16(pf, vf, zero, 0, 0, 0);
#pragma unroll
        for (int r = 0; r < 4; r++) {
            const int row = quad * 4 + r;
            o[(size_t)(b * SS + q0 + row) * DD + h * HDD + dt * 16 + l16] =
                (bf16)(ov[r] * rl[r]);
        }
    }
}

// ---------------- launch ----------------
extern "C" void kernel_launch(void* const* d_in, const int* in_sizes, int n_in,
                              void* d_out, int out_size, void* d_ws, size_t ws_size,
                              hipStream_t stream)
{
    (void)in_sizes; (void)n_in; (void)out_size; (void)ws_size;
    const float* x    = (const float*)d_in[0];
    const float* ln1g = (const float*)d_in[1];
    const float* ln1b = (const float*)d_in[2];
    const float* Wqkv = (const float*)d_in[3];
    const float* bqkv = (const float*)d_in[4];
    const float* Wout = (const float*)d_in[5];
    const float* bout = (const float*)d_in[6];
    const float* ln2g = (const float*)d_in[7];
    const float* ln2b = (const float*)d_in[8];
    const float* W1   = (const float*)d_in[9];
    const float* b1   = (const float*)d_in[10];
    const float* W2   = (const float*)d_in[11];
    const float* b2   = (const float*)d_in[12];

    // Workspace (56 MiB peak):
    //   [0,16M)  W region. Phase A: Wqkv_bf @0..6M, Wout_bf @6..8M.
    //            Phase B: W1_bf @0..8M, W2_bf @8..16M (conv after out-proj).
    //   [16,48M) P region. Phase A: qkv bf16 24 MiB. Phase B: h1 bf16 32 MiB.
    //   [48,56M) H region: h (LN1 out) -> o (attn out) -> xn (LN2 out), serially.
    //   x1 fp32 lives in d_out; MLP2 split-K atomically accumulates in place.
    const size_t MB = (size_t)1 << 20;
    char* ws = (char*)d_ws;
    bf16* wqkv_bf = (bf16*)(ws);
    bf16* wout_bf = (bf16*)(ws + 6 * MB);
    bf16* w1_bf   = (bf16*)(ws);
    bf16* w2_bf   = (bf16*)(ws + 8 * MB);
    bf16* qkv     = (bf16*)(ws + 16 * MB);
    bf16* h1      = (bf16*)(ws + 16 * MB);
    bf16* hbuf    = (bf16*)(ws + 48 * MB);   // h, then o, then xn
    float* x1     = (float*)d_out;

    const dim3 blk(256);

    // Phase A: weights for QKV + out-proj
    conv_kernel<<<(3 * DD * DD / 8) / 256, blk, 0, stream>>>(Wqkv, wqkv_bf, 3 * DD * DD / 8);
    conv_kernel<<<(DD * DD / 8) / 256, blk, 0, stream>>>(Wout, wout_bf, DD * DD / 8);
    // h = LN1(x)
    ln_kernel<<<NTOK, blk, 0, stream>>>(x, ln1g, ln1b, hbuf);
    // qkv = h @ Wqkv^T + bqkv           (M=4096, N=3072, K=1024; 768 blocks = 3/CU)
    gemm_glds<128, 0, 0, 0><<<dim3(24, 32), blk, 0, stream>>>(
        hbuf, wqkv_bf, bqkv, nullptr, qkv, 3 * DD, DD);
    // o = attention(qkv)  (o overwrites h — h dead)
    attn_kernel<<<BB * HH * (SS / 16) / 4, blk, 0, stream>>>(qkv, hbuf);
    // x1 = x + o @ Wout^T + bout        (fp32 into d_out; M=4096, N=1024, K=1024)
    gemm_glds<64, 0, 2, 1><<<dim3(8, 64), blk, 0, stream>>>(
        hbuf, wout_bf, bout, x, x1, DD, DD);

    // Phase B: weights for MLP
    conv_kernel<<<(DFFD * DD / 8) / 256, blk, 0, stream>>>(W1, w1_bf, DFFD * DD / 8);
    conv_kernel<<<(DFFD * DD / 8) / 256, blk, 0, stream>>>(W2, w2_bf, DFFD * DD / 8);
    // xn = LN2(x1)   (xn overwrites o — o dead)
    ln_kernel<<<NTOK, blk, 0, stream>>>(x1, ln2g, ln2b, hbuf);
    // h1 = gelu(xn @ W1^T + b1)         (M=4096, N=4096, K=1024; 1024 blocks = 4/CU)
    gemm_glds<128, 1, 0, 0><<<dim3(32, 32), blk, 0, stream>>>(
        hbuf, w1_bf, b1, nullptr, h1, DFFD, DD);
    // out = x1 + h1 @ W2^T + b2         (split-K=2, TM=128: 512 blocks = 2/CU;
    //   8.4M atomics into pre-primed x1 in d_out)
    gemm_glds<128, 0, 3, 1><<<dim3(8, 32, 2), blk, 0, stream>>>(
        h1, w2_bf, b2, nullptr, x1, DD, DFFD);
}

// Round 8
// 302.108 us; speedup vs baseline: 1.0462x; 1.0462x over previous
//
#include <hip/hip_runtime.h>
#include <hip/hip_bf16.h>
#include <cmath>

typedef __bf16 bf16;
typedef __bf16 bf16x4 __attribute__((ext_vector_type(4)));
typedef __bf16 bf16x8 __attribute__((ext_vector_type(8)));
typedef float f32x4 __attribute__((ext_vector_type(4)));

#define BB 2
#define SS 2048
#define DD 1024
#define HH 16
#define WW 16
#define HDD 64
#define DFFD 4096
#define NTOK (BB*SS)

// gelu(x) = x * sigmoid(2*sqrt(2/pi)*(x+0.044715x^3))  == tanh-approx gelu
__device__ __forceinline__ float gelu_f(float x) {
    const float k = 1.5957691216057308f;  // 2*sqrt(2/pi)
    float u = k * (x + 0.044715f * x * x * x);
    return x / (1.0f + __expf(-u));
}

// ---- async global->LDS 16B/lane. LDS dest = wave-uniform base; HW adds lane*16. ----
__device__ __forceinline__ void glds16(const bf16* g, const bf16* l) {
    __builtin_amdgcn_global_load_lds(
        (const __attribute__((address_space(1))) void*)(uintptr_t)(const void*)g,
        (__attribute__((address_space(3))) void*)(unsigned)(uintptr_t)(const void*)l,
        16, 0, 0);
}

// ---------------- fp32 -> bf16 convert, 8 elems/thread ----------------
__global__ __launch_bounds__(256) void conv_kernel(
    const float* __restrict__ src, bf16* __restrict__ dst, int n8)
{
    int i = blockIdx.x * 256 + threadIdx.x;
    if (i >= n8) return;
    f32x4 a = *(const f32x4*)(src + (size_t)i * 8);
    f32x4 b = *(const f32x4*)(src + (size_t)i * 8 + 4);
    bf16x8 v;
#pragma unroll
    for (int j = 0; j < 4; j++) { v[j] = (bf16)a[j]; v[4 + j] = (bf16)b[j]; }
    *(bf16x8*)(dst + (size_t)i * 8) = v;
}

// ---------------- fused LayerNorm: fp32 row -> bf16 row, one block/row ----------------
__global__ __launch_bounds__(256) void ln_kernel(
    const float* __restrict__ x, const float* __restrict__ g, const float* __restrict__ b,
    bf16* __restrict__ out)
{
    const int row = blockIdx.x, t = threadIdx.x;
    f32x4 v = *(const f32x4*)(x + (size_t)row * DD + t * 4);
    float s  = v[0] + v[1] + v[2] + v[3];
    float s2 = v[0]*v[0] + v[1]*v[1] + v[2]*v[2] + v[3]*v[3];
#pragma unroll
    for (int off = 32; off >= 1; off >>= 1) {
        s  += __shfl_xor(s,  off, 64);
        s2 += __shfl_xor(s2, off, 64);
    }
    __shared__ float red[8];
    const int wave = t >> 6;
    if ((t & 63) == 0) { red[wave] = s; red[4 + wave] = s2; }
    __syncthreads();
    float ts  = red[0] + red[1] + red[2] + red[3];
    float ts2 = red[4] + red[5] + red[6] + red[7];
    float mean = ts * (1.0f / DD);
    float var  = ts2 * (1.0f / DD) - mean * mean;
    float rstd = rsqrtf(var + 1e-5f);
    f32x4 gv = *(const f32x4*)(g + t * 4);
    f32x4 bv = *(const f32x4*)(b + t * 4);
    bf16x4 o;
#pragma unroll
    for (int i = 0; i < 4; i++) o[i] = (bf16)((v[i] - mean) * rstd * gv[i] + bv[i]);
    *(bf16x4*)(out + (size_t)row * DD + t * 4) = o;
}

// ======== bf16 MFMA GEMM: ring-3 counted-vmcnt pipeline on the 128-tile shape ========
// C[M,N] = A[M,K] @ W[N,K]^T + bias.  256 thr, TM=128 (waves 2x2, 4x4 frags) or
// TM=64 (1x4, 4x2). BN=128, BK=32.
// R7 k-loop (replaces 2ph __syncthreads, whose implicit vmcnt(0) drain exposed a
// full HBM/L2 round-trip per 32-K step -> MfmaUtil 19%):
//   prologue: stage(tile0), stage(tile1)
//   iter t:   vmcnt(L)   (L = glds16/stage; only tile t+1's loads still in flight)
//             s_barrier  (tile t visible to all waves; loads for t+1 stay in flight)
//             ds_read frags ; stage(t+2) ; lgkmcnt(0) ; MFMA
// One barrier/iter, vmcnt never 0 until the tail (T4). Prefetch depth 2 tiles.
// WAR: stage(t+2) overwrites ring slot (t-1)%3, whose ds_reads completed before
// each wave's lgkm(0) at iter t-1, hence before all waves crossed barrier(t).
// LDS = 3*(TM+128)*32*2B = 48/36 KB -> 3-4 blocks/CU co-resident (keeps the m114
// cross-block overlap the 512-thr/128KB 8p variants lost).
// T2 swizzle (verified 0-conflict in R4, same fragment geometry): global source
// col-group qsw=(t&3)^((srow>>1)&3) pre-inverts; read slot rsl=(quad^((l16>>1)&3))*8.
// RESID: 2=add fp32 resid (may alias fp32 Cout: same elem, same thread).
// 3=split-K over gridDim.z, unsafeAtomicAdd into pre-primed fp32 Cout, bias at z==0.
// ACT: 1=gelu. OUTF32: 1=fp32 out, 0=bf16.
template<int TM, int ACT, int RESID, int OUTF32>
__global__ __launch_bounds__(256) void gemm_glds(
    const bf16* __restrict__ A, const bf16* __restrict__ Bw,
    const float* __restrict__ bias,
    const float* resid, void* __restrict__ Cout, int N, int K)
{
    constexpr int MI = 4;
    constexpr int NJ = (TM == 128) ? 4 : 2;
    __shared__ __align__(16) bf16 As[3 * TM * 32];
    __shared__ __align__(16) bf16 Bs[3 * 128 * 32];
    const int t = threadIdx.x;
    const int m0 = blockIdx.y * TM, n0 = blockIdx.x * 128;
    const int lane = t & 63, w = t >> 6;
    const int wm = (TM == 128) ? (w & 1) * 64 : 0;
    const int wn = (TM == 128) ? (w >> 1) * 64 : w * 32;
    const int quad = lane >> 4, l16 = lane & 15;
    const int srow = t >> 2;                       // 4 lanes/row, 16 B each
    const int qsw  = (t & 3) ^ ((srow >> 1) & 3);  // T2 inverse perm on global source

    const bf16* Ag = A  + (size_t)(m0 + srow) * K + qsw * 8;
    const bf16* Bg = Bw + (size_t)(n0 + srow) * K + qsw * 8;

    int k_lo = 0, k_hi = K;
    if (RESID == 3) {                 // split-K: this block handles one K-slice
        const int ks = K / gridDim.z;
        k_lo = blockIdx.z * ks;
        k_hi = k_lo + ks;
    }

    auto stage = [&](int buf, int k0) {
        const bf16* AsW = As + buf * (TM * 32) + w * 512;
        const bf16* BsW = Bs + buf * (128 * 32) + w * 512;
        glds16(Ag + k0, AsW);
        if (TM == 128) glds16(Ag + (size_t)64 * K + k0, AsW + 2048);
        glds16(Bg + k0, BsW);
        glds16(Bg + (size_t)64 * K + k0, BsW + 2048);
    };

    const f32x4 zero = {0.f, 0.f, 0.f, 0.f};
    f32x4 acc[MI][NJ];
#pragma unroll
    for (int i = 0; i < MI; i++)
#pragma unroll
        for (int j = 0; j < NJ; j++) acc[i][j] = zero;

    const int nsteps = (k_hi - k_lo) >> 5;
    stage(0, k_lo);
    if (nsteps > 1) stage(1, k_lo + 32);

    const int rsl = (quad ^ ((l16 >> 1) & 3)) * 8;   // T2 read-side slot (bf16 off)
    int cur = 0, nxt2 = 2;                            // step%3, (step+2)%3
    for (int step = 0; step < nsteps; ++step) {
        // counted vmcnt: tile t+1's L loads may stay in flight; tile t's landed.
        if (step < nsteps - 1) {
            if (TM == 128) asm volatile("s_waitcnt vmcnt(4)" ::: "memory");
            else           asm volatile("s_waitcnt vmcnt(3)" ::: "memory");
        } else {
            asm volatile("s_waitcnt vmcnt(0)" ::: "memory");
        }
        __builtin_amdgcn_s_barrier();
        const bf16* Ab = As + cur * (TM * 32);
        const bf16* Bb = Bs + cur * (128 * 32);
        bf16x8 af[MI], bfr[NJ];
#pragma unroll
        for (int i = 0; i < MI; i++)
            af[i] = *(const bf16x8*)(Ab + (wm + i * 16 + l16) * 32 + rsl);
#pragma unroll
        for (int j = 0; j < NJ; j++)
            bfr[j] = *(const bf16x8*)(Bb + (wn + j * 16 + l16) * 32 + rsl);
        if (step + 2 < nsteps) stage(nxt2, k_lo + ((step + 2) << 5));
        asm volatile("s_waitcnt lgkmcnt(0)" ::: "memory");
        __builtin_amdgcn_sched_barrier(0);
#pragma unroll
        for (int i = 0; i < MI; i++)
#pragma unroll
            for (int j = 0; j < NJ; j++)
                acc[i][j] = __builtin_amdgcn_mfma_f32_16x16x32_bf16(af[i], bfr[j], acc[i][j], 0, 0, 0);
        cur  = (cur  + 1 == 3) ? 0 : cur  + 1;
        nxt2 = (nxt2 + 1 == 3) ? 0 : nxt2 + 1;
    }

#pragma unroll
    for (int i = 0; i < MI; i++) {
#pragma unroll
        for (int j = 0; j < NJ; j++) {
            int col = n0 + wn + j * 16 + l16;
            float bv = bias[col];
            if (RESID == 3 && blockIdx.z != 0) bv = 0.0f;
#pragma unroll
            for (int r = 0; r < 4; r++) {
                int row = m0 + wm + i * 16 + quad * 4 + r;
                float val = acc[i][j][r] + bv;
                if (ACT == 1) val = gelu_f(val);
                size_t idx = (size_t)row * N + col;
                if (RESID == 2) val += resid[idx];
                if (RESID == 3) {
                    unsafeAtomicAdd(&((float*)Cout)[idx], val);   // HW global_atomic_add_f32
                } else if (OUTF32) {
                    ((float*)Cout)[idx] = val;
                } else {
                    ((bf16*)Cout)[idx] = (bf16)val;
                }
            }
        }
    }
}

// ---------------- Sliding-window causal attention, MFMA-tiled ----------------
// One wave per (b, h, 16-query block); window W=16 -> two 16-key tiles.
// QK^T: 4 MFMAs, A/B frags direct from global. Softmax: 16-lane butterfly.
// P via 1KB wave-private LDS; V staged per-wave via glds16, consumed transposed.
__global__ __launch_bounds__(256) void attn_kernel(
    const bf16* __restrict__ qkv, bf16* __restrict__ o)
{
    __shared__ __align__(16) bf16 Vlds[4][32 * 64];
    __shared__ __align__(16) bf16 Plds[4][16 * 32];
    const int t = threadIdx.x;
    const int w = t >> 6, lane = t & 63;
    const int quad = lane >> 4, l16 = lane & 15;
    const int gw = blockIdx.x * 4 + w;
    const int qb = gw & 127;
    const int h  = (gw >> 7) & (HH - 1);
    const int b  = gw >> 11;
    const int q0 = qb << 4;
    const size_t rs = 3 * DD;
    const bf16* Qb = qkv + (size_t)b * SS * rs + h * HDD;
    const bf16* Kb = Qb + DD;
    const bf16* Vb = Qb + 2 * DD;
    bf16* Vw = Vlds[w];
    bf16* Pw = Plds[w];

    {
        const int sub = lane >> 3;
        const int dc  = (lane & 7) * 8;
#pragma unroll
        for (int c = 0; c < 4; c++) {
            int key = q0 - 16 + c * 8 + sub;
            if (key < 0) key = 0;
            glds16(Vb + (size_t)key * rs + dc, Vw + c * 512);
        }
    }

    const int qrow = q0 + l16;
    int kr0 = q0 - 16 + l16; if (kr0 < 0) kr0 = 0;
    bf16x8 qf0  = *(const bf16x8*)(Qb + (size_t)qrow * rs + quad * 8);
    bf16x8 qf1  = *(const bf16x8*)(Qb + (size_t)qrow * rs + 32 + quad * 8);
    bf16x8 kf0a = *(const bf16x8*)(Kb + (size_t)kr0  * rs + quad * 8);
    bf16x8 kf0b = *(const bf16x8*)(Kb + (size_t)kr0  * rs + 32 + quad * 8);
    bf16x8 kf1a = *(const bf16x8*)(Kb + (size_t)qrow * rs + quad * 8);
    bf16x8 kf1b = *(const bf16x8*)(Kb + (size_t)qrow * rs + 32 + quad * 8);

    const f32x4 zero = {0.f, 0.f, 0.f, 0.f};
    f32x4 acc0 = __builtin_amdgcn_mfma_f32_16x16x32_bf16(qf0, kf0a, zero, 0, 0, 0);
    acc0 = __builtin_amdgcn_mfma_f32_16x16x32_bf16(qf1, kf0b, acc0, 0, 0, 0);
    f32x4 acc1 = __builtin_amdgcn_mfma_f32_16x16x32_bf16(qf0, kf1a, zero, 0, 0, 0);
    acc1 = __builtin_amdgcn_mfma_f32_16x16x32_bf16(qf1, kf1b, acc1, 0, 0, 0);

    float rl[4];
#pragma unroll
    for (int r = 0; r < 4; r++) {
        const int row = quad * 4 + r;
        float s0 = (l16 > row && q0 - 16 + l16 >= 0) ? acc0[r] * 0.125f : -1e30f;
        float s1 = (l16 <= row)                      ? acc1[r] * 0.125f : -1e30f;
        float m = fmaxf(s0, s1);
        m = fmaxf(m, __shfl_xor(m, 1, 64));
        m = fmaxf(m, __shfl_xor(m, 2, 64));
        m = fmaxf(m, __shfl_xor(m, 4, 64));
        m = fmaxf(m, __shfl_xor(m, 8, 64));
        float e0 = __expf(s0 - m), e1 = __expf(s1 - m);
        float sum = e0 + e1;
        sum += __shfl_xor(sum, 1, 64);
        sum += __shfl_xor(sum, 2, 64);
        sum += __shfl_xor(sum, 4, 64);
        sum += __shfl_xor(sum, 8, 64);
        rl[r] = 1.0f / sum;
        Pw[row * 32 + l16]      = (bf16)e0;
        Pw[row * 32 + 16 + l16] = (bf16)e1;
    }

    asm volatile("s_waitcnt vmcnt(0)" ::: "memory");
    bf16x8 pf = *(const bf16x8*)(Pw + l16 * 32 + quad * 8);
#pragma unroll
    for (int dt = 0; dt < 4; dt++) {
        bf16x8 vf;
#pragma unroll
        for (int jj = 0; jj < 8; jj++)
            vf[jj] = Vw[(quad * 8 + jj) * 64 + dt * 16 + l16];
        f32x4 ov = __builtin_amdgcn_mfma_f32_16x16x32_bf16(pf, vf, zero, 0, 0, 0);
#pragma unroll
        for (int r = 0; r < 4; r++) {
            const int row = quad * 4 + r;
            o[(size_t)(b * SS + q0 + row) * DD + h * HDD + dt * 16 + l16] =
                (bf16)(ov[r] * rl[r]);
        }
    }
}

// ---------------- launch ----------------
extern "C" void kernel_launch(void* const* d_in, const int* in_sizes, int n_in,
                              void* d_out, int out_size, void* d_ws, size_t ws_size,
                              hipStream_t stream)
{
    (void)in_sizes; (void)n_in; (void)out_size; (void)ws_size;
    const float* x    = (const float*)d_in[0];
    const float* ln1g = (const float*)d_in[1];
    const float* ln1b = (const float*)d_in[2];
    const float* Wqkv = (const float*)d_in[3];
    const float* bqkv = (const float*)d_in[4];
    const float* Wout = (const float*)d_in[5];
    const float* bout = (const float*)d_in[6];
    const float* ln2g = (const float*)d_in[7];
    const float* ln2b = (const float*)d_in[8];
    const float* W1   = (const float*)d_in[9];
    const float* b1   = (const float*)d_in[10];
    const float* W2   = (const float*)d_in[11];
    const float* b2   = (const float*)d_in[12];

    // Workspace (56 MiB peak):
    //   [0,16M)  W region. Phase A: Wqkv_bf @0..6M, Wout_bf @6..8M.
    //            Phase B: W1_bf @0..8M, W2_bf @8..16M (conv after out-proj).
    //   [16,48M) P region. Phase A: qkv bf16 24 MiB. Phase B: h1 bf16 32 MiB.
    //   [48,56M) H region: h (LN1 out) -> o (attn out) -> xn (LN2 out), serially.
    //   x1 fp32 lives in d_out; MLP2 split-K atomically accumulates in place.
    const size_t MB = (size_t)1 << 20;
    char* ws = (char*)d_ws;
    bf16* wqkv_bf = (bf16*)(ws);
    bf16* wout_bf = (bf16*)(ws + 6 * MB);
    bf16* w1_bf   = (bf16*)(ws);
    bf16* w2_bf   = (bf16*)(ws + 8 * MB);
    bf16* qkv     = (bf16*)(ws + 16 * MB);
    bf16* h1      = (bf16*)(ws + 16 * MB);
    bf16* hbuf    = (bf16*)(ws + 48 * MB);   // h, then o, then xn
    float* x1     = (float*)d_out;

    const dim3 blk(256);

    // Phase A: weights for QKV + out-proj
    conv_kernel<<<(3 * DD * DD / 8) / 256, blk, 0, stream>>>(Wqkv, wqkv_bf, 3 * DD * DD / 8);
    conv_kernel<<<(DD * DD / 8) / 256, blk, 0, stream>>>(Wout, wout_bf, DD * DD / 8);
    // h = LN1(x)
    ln_kernel<<<NTOK, blk, 0, stream>>>(x, ln1g, ln1b, hbuf);
    // qkv = h @ Wqkv^T + bqkv           (M=4096, N=3072, K=1024; 768 blocks = 3/CU)
    gemm_glds<128, 0, 0, 0><<<dim3(24, 32), blk, 0, stream>>>(
        hbuf, wqkv_bf, bqkv, nullptr, qkv, 3 * DD, DD);
    // o = attention(qkv)  (o overwrites h — h dead)
    attn_kernel<<<BB * HH * (SS / 16) / 4, blk, 0, stream>>>(qkv, hbuf);
    // x1 = x + o @ Wout^T + bout        (fp32 into d_out; M=4096, N=1024, K=1024)
    gemm_glds<64, 0, 2, 1><<<dim3(8, 64), blk, 0, stream>>>(
        hbuf, wout_bf, bout, x, x1, DD, DD);

    // Phase B: weights for MLP
    conv_kernel<<<(DFFD * DD / 8) / 256, blk, 0, stream>>>(W1, w1_bf, DFFD * DD / 8);
    conv_kernel<<<(DFFD * DD / 8) / 256, blk, 0, stream>>>(W2, w2_bf, DFFD * DD / 8);
    // xn = LN2(x1)   (xn overwrites o — o dead)
    ln_kernel<<<NTOK, blk, 0, stream>>>(x1, ln2g, ln2b, hbuf);
    // h1 = gelu(xn @ W1^T + b1)         (M=4096, N=4096, K=1024; 1024 blocks = 4/CU)
    gemm_glds<128, 1, 0, 0><<<dim3(32, 32), blk, 0, stream>>>(
        hbuf, w1_bf, b1, nullptr, h1, DFFD, DD);
    // out = x1 + h1 @ W2^T + b2         (split-K=2, TM=128: 512 blocks = 2/CU;
    //   8.4M atomics into pre-primed x1 in d_out)
    gemm_glds<128, 0, 3, 1><<<dim3(8, 32, 2), blk, 0, stream>>>(
        h1, w2_bf, b2, nullptr, x1, DD, DFFD);
}

// Round 9
// 300.594 us; speedup vs baseline: 1.0514x; 1.0050x over previous
//
#include <hip/hip_runtime.h>
#include <hip/hip_bf16.h>
#include <cmath>

typedef __bf16 bf16;
typedef __bf16 bf16x4 __attribute__((ext_vector_type(4)));
typedef __bf16 bf16x8 __attribute__((ext_vector_type(8)));
typedef float f32x4 __attribute__((ext_vector_type(4)));

#define BB 2
#define SS 2048
#define DD 1024
#define HH 16
#define WW 16
#define HDD 64
#define DFFD 4096
#define NTOK (BB*SS)

// gelu(x) = x * sigmoid(2*sqrt(2/pi)*(x+0.044715x^3))  == tanh-approx gelu
__device__ __forceinline__ float gelu_f(float x) {
    const float k = 1.5957691216057308f;  // 2*sqrt(2/pi)
    float u = k * (x + 0.044715f * x * x * x);
    return x / (1.0f + __expf(-u));
}

// ---- async global->LDS 16B/lane. LDS dest = wave-uniform base; HW adds lane*16. ----
__device__ __forceinline__ void glds16(const bf16* g, const bf16* l) {
    __builtin_amdgcn_global_load_lds(
        (const __attribute__((address_space(1))) void*)(uintptr_t)(const void*)g,
        (__attribute__((address_space(3))) void*)(unsigned)(uintptr_t)(const void*)l,
        16, 0, 0);
}

// ---------------- fp32 -> bf16 convert, 8 elems/thread ----------------
__global__ __launch_bounds__(256) void conv_kernel(
    const float* __restrict__ src, bf16* __restrict__ dst, int n8)
{
    int i = blockIdx.x * 256 + threadIdx.x;
    if (i >= n8) return;
    f32x4 a = *(const f32x4*)(src + (size_t)i * 8);
    f32x4 b = *(const f32x4*)(src + (size_t)i * 8 + 4);
    bf16x8 v;
#pragma unroll
    for (int j = 0; j < 4; j++) { v[j] = (bf16)a[j]; v[4 + j] = (bf16)b[j]; }
    *(bf16x8*)(dst + (size_t)i * 8) = v;
}

// ---------------- fused LayerNorm: fp32 row -> bf16 row, one block/row ----------------
__global__ __launch_bounds__(256) void ln_kernel(
    const float* __restrict__ x, const float* __restrict__ g, const float* __restrict__ b,
    bf16* __restrict__ out)
{
    const int row = blockIdx.x, t = threadIdx.x;
    f32x4 v = *(const f32x4*)(x + (size_t)row * DD + t * 4);
    float s  = v[0] + v[1] + v[2] + v[3];
    float s2 = v[0]*v[0] + v[1]*v[1] + v[2]*v[2] + v[3]*v[3];
#pragma unroll
    for (int off = 32; off >= 1; off >>= 1) {
        s  += __shfl_xor(s,  off, 64);
        s2 += __shfl_xor(s2, off, 64);
    }
    __shared__ float red[8];
    const int wave = t >> 6;
    if ((t & 63) == 0) { red[wave] = s; red[4 + wave] = s2; }
    __syncthreads();
    float ts  = red[0] + red[1] + red[2] + red[3];
    float ts2 = red[4] + red[5] + red[6] + red[7];
    float mean = ts * (1.0f / DD);
    float var  = ts2 * (1.0f / DD) - mean * mean;
    float rstd = rsqrtf(var + 1e-5f);
    f32x4 gv = *(const f32x4*)(g + t * 4);
    f32x4 bv = *(const f32x4*)(b + t * 4);
    bf16x4 o;
#pragma unroll
    for (int i = 0; i < 4; i++) o[i] = (bf16)((v[i] - mean) * rstd * gv[i] + bv[i]);
    *(bf16x4*)(out + (size_t)row * DD + t * 4) = o;
}

// ======== bf16 MFMA GEMM: ring-3 counted-vmcnt pipeline + T1 XCD swizzle ========
// C[M,N] = A[M,K] @ W[N,K]^T + bias.  256 thr, TM=128 (waves 2x2, 4x4 frags) or
// TM=64 (1x4, 4x2). BN=128, BK=32.
// k-loop (R7, measured: MLP1 72.4 -> 64.1 us, conflicts 0):
//   prologue stage(0),stage(1); iter t: vmcnt(L) -> s_barrier -> ds_read frags ->
//   stage(t+2) -> lgkmcnt(0) -> MFMA.  One barrier/iter, vmcnt never 0 until tail.
//   WAR: stage(t+2) overwrites slot (t-1)%3 whose reads drained at iter t-1's lgkm(0).
// T1 XCD swizzle (R8): default round-robin dispatch scatters same-A-panel blocks
// across all 8 XCD L2s -> every XCD fetches every panel (MLP1 FETCH 135.8 MB vs
// 16 MiB ideal). swz=(bid&7)*cpx+(bid>>3) gives each XCD a CONTIGUOUS tile range
// (e.g. 4 full M-rows on MLP1): A-panels/XCD 32->4. Requires nbxy%8==0 (all grids:
// 768/1024/512/256). z (split-K) not swizzled.
// T2 swizzle (R4-verified 0-conflict): global source col-group qsw pre-inverts;
// read slot rsl=(quad^((l16>>1)&3))*8.
// RESID: 2=add fp32 resid (may alias Cout, same elem same thread). 3=split-K over
// gridDim.z, unsafeAtomicAdd into pre-primed fp32 Cout, bias at z==0. ACT: 1=gelu.
template<int TM, int ACT, int RESID, int OUTF32>
__global__ __launch_bounds__(256) void gemm_glds(
    const bf16* __restrict__ A, const bf16* __restrict__ Bw,
    const float* __restrict__ bias,
    const float* resid, void* __restrict__ Cout, int N, int K)
{
    constexpr int MI = 4;
    constexpr int NJ = (TM == 128) ? 4 : 2;
    __shared__ __align__(16) bf16 As[3 * TM * 32];
    __shared__ __align__(16) bf16 Bs[3 * 128 * 32];
    const int t = threadIdx.x;
    // T1: bijective XCD swizzle over linearized xy grid
    const int nbxy = gridDim.x * gridDim.y;
    const int bid  = blockIdx.y * gridDim.x + blockIdx.x;
    const int cpx  = nbxy >> 3;
    const int swz  = (bid & 7) * cpx + (bid >> 3);
    const int m0 = (swz / gridDim.x) * TM;
    const int n0 = (swz % gridDim.x) * 128;
    const int lane = t & 63, w = t >> 6;
    const int wm = (TM == 128) ? (w & 1) * 64 : 0;
    const int wn = (TM == 128) ? (w >> 1) * 64 : w * 32;
    const int quad = lane >> 4, l16 = lane & 15;
    const int srow = t >> 2;                       // 4 lanes/row, 16 B each
    const int qsw  = (t & 3) ^ ((srow >> 1) & 3);  // T2 inverse perm on global source

    const bf16* Ag = A  + (size_t)(m0 + srow) * K + qsw * 8;
    const bf16* Bg = Bw + (size_t)(n0 + srow) * K + qsw * 8;

    int k_lo = 0, k_hi = K;
    if (RESID == 3) {                 // split-K: this block handles one K-slice
        const int ks = K / gridDim.z;
        k_lo = blockIdx.z * ks;
        k_hi = k_lo + ks;
    }

    auto stage = [&](int buf, int k0) {
        const bf16* AsW = As + buf * (TM * 32) + w * 512;
        const bf16* BsW = Bs + buf * (128 * 32) + w * 512;
        glds16(Ag + k0, AsW);
        if (TM == 128) glds16(Ag + (size_t)64 * K + k0, AsW + 2048);
        glds16(Bg + k0, BsW);
        glds16(Bg + (size_t)64 * K + k0, BsW + 2048);
    };

    const f32x4 zero = {0.f, 0.f, 0.f, 0.f};
    f32x4 acc[MI][NJ];
#pragma unroll
    for (int i = 0; i < MI; i++)
#pragma unroll
        for (int j = 0; j < NJ; j++) acc[i][j] = zero;

    const int nsteps = (k_hi - k_lo) >> 5;
    stage(0, k_lo);
    if (nsteps > 1) stage(1, k_lo + 32);

    const int rsl = (quad ^ ((l16 >> 1) & 3)) * 8;   // T2 read-side slot (bf16 off)
    int cur = 0, nxt2 = 2;                            // step%3, (step+2)%3
    for (int step = 0; step < nsteps; ++step) {
        // counted vmcnt: tile t+1's L loads may stay in flight; tile t's landed.
        if (step < nsteps - 1) {
            if (TM == 128) asm volatile("s_waitcnt vmcnt(4)" ::: "memory");
            else           asm volatile("s_waitcnt vmcnt(3)" ::: "memory");
        } else {
            asm volatile("s_waitcnt vmcnt(0)" ::: "memory");
        }
        __builtin_amdgcn_s_barrier();
        const bf16* Ab = As + cur * (TM * 32);
        const bf16* Bb = Bs + cur * (128 * 32);
        bf16x8 af[MI], bfr[NJ];
#pragma unroll
        for (int i = 0; i < MI; i++)
            af[i] = *(const bf16x8*)(Ab + (wm + i * 16 + l16) * 32 + rsl);
#pragma unroll
        for (int j = 0; j < NJ; j++)
            bfr[j] = *(const bf16x8*)(Bb + (wn + j * 16 + l16) * 32 + rsl);
        if (step + 2 < nsteps) stage(nxt2, k_lo + ((step + 2) << 5));
        asm volatile("s_waitcnt lgkmcnt(0)" ::: "memory");
        __builtin_amdgcn_sched_barrier(0);
#pragma unroll
        for (int i = 0; i < MI; i++)
#pragma unroll
            for (int j = 0; j < NJ; j++)
                acc[i][j] = __builtin_amdgcn_mfma_f32_16x16x32_bf16(af[i], bfr[j], acc[i][j], 0, 0, 0);
        cur  = (cur  + 1 == 3) ? 0 : cur  + 1;
        nxt2 = (nxt2 + 1 == 3) ? 0 : nxt2 + 1;
    }

#pragma unroll
    for (int i = 0; i < MI; i++) {
#pragma unroll
        for (int j = 0; j < NJ; j++) {
            int col = n0 + wn + j * 16 + l16;
            float bv = bias[col];
            if (RESID == 3 && blockIdx.z != 0) bv = 0.0f;
#pragma unroll
            for (int r = 0; r < 4; r++) {
                int row = m0 + wm + i * 16 + quad * 4 + r;
                float val = acc[i][j][r] + bv;
                if (ACT == 1) val = gelu_f(val);
                size_t idx = (size_t)row * N + col;
                if (RESID == 2) val += resid[idx];
                if (RESID == 3) {
                    unsafeAtomicAdd(&((float*)Cout)[idx], val);   // HW global_atomic_add_f32
                } else if (OUTF32) {
                    ((float*)Cout)[idx] = val;
                } else {
                    ((bf16*)Cout)[idx] = (bf16)val;
                }
            }
        }
    }
}

// ---------------- Sliding-window causal attention, MFMA-tiled ----------------
// One wave per (b, h, 16-query block); window W=16 -> two 16-key tiles.
// QK^T: 4 MFMAs, A/B frags direct from global. Softmax: 16-lane butterfly.
// P via 1KB wave-private LDS; V staged per-wave via glds16, consumed transposed.
__global__ __launch_bounds__(256) void attn_kernel(
    const bf16* __restrict__ qkv, bf16* __restrict__ o)
{
    __shared__ __align__(16) bf16 Vlds[4][32 * 64];
    __shared__ __align__(16) bf16 Plds[4][16 * 32];
    const int t = threadIdx.x;
    const int w = t >> 6, lane = t & 63;
    const int quad = lane >> 4, l16 = lane & 15;
    const int gw = blockIdx.x * 4 + w;
    const int qb = gw & 127;
    const int h  = (gw >> 7) & (HH - 1);
    const int b  = gw >> 11;
    const int q0 = qb << 4;
    const size_t rs = 3 * DD;
    const bf16* Qb = qkv + (size_t)b * SS * rs + h * HDD;
    const bf16* Kb = Qb + DD;
    const bf16* Vb = Qb + 2 * DD;
    bf16* Vw = Vlds[w];
    bf16* Pw = Plds[w];

    {
        const int sub = lane >> 3;
        const int dc  = (lane & 7) * 8;
#pragma unroll
        for (int c = 0; c < 4; c++) {
            int key = q0 - 16 + c * 8 + sub;
            if (key < 0) key = 0;
            glds16(Vb + (size_t)key * rs + dc, Vw + c * 512);
        }
    }

    const int qrow = q0 + l16;
    int kr0 = q0 - 16 + l16; if (kr0 < 0) kr0 = 0;
    bf16x8 qf0  = *(const bf16x8*)(Qb + (size_t)qrow * rs + quad * 8);
    bf16x8 qf1  = *(const bf16x8*)(Qb + (size_t)qrow * rs + 32 + quad * 8);
    bf16x8 kf0a = *(const bf16x8*)(Kb + (size_t)kr0  * rs + quad * 8);
    bf16x8 kf0b = *(const bf16x8*)(Kb + (size_t)kr0  * rs + 32 + quad * 8);
    bf16x8 kf1a = *(const bf16x8*)(Kb + (size_t)qrow * rs + quad * 8);
    bf16x8 kf1b = *(const bf16x8*)(Kb + (size_t)qrow * rs + 32 + quad * 8);

    const f32x4 zero = {0.f, 0.f, 0.f, 0.f};
    f32x4 acc0 = __builtin_amdgcn_mfma_f32_16x16x32_bf16(qf0, kf0a, zero, 0, 0, 0);
    acc0 = __builtin_amdgcn_mfma_f32_16x16x32_bf16(qf1, kf0b, acc0, 0, 0, 0);
    f32x4 acc1 = __builtin_amdgcn_mfma_f32_16x16x32_bf16(qf0, kf1a, zero, 0, 0, 0);
    acc1 = __builtin_amdgcn_mfma_f32_16x16x32_bf16(qf1, kf1b, acc1, 0, 0, 0);

    float rl[4];
#pragma unroll
    for (int r = 0; r < 4; r++) {
        const int row = quad * 4 + r;
        float s0 = (l16 > row && q0 - 16 + l16 >= 0) ? acc0[r] * 0.125f : -1e30f;
        float s1 = (l16 <= row)                      ? acc1[r] * 0.125f : -1e30f;
        float m = fmaxf(s0, s1);
        m = fmaxf(m, __shfl_xor(m, 1, 64));
        m = fmaxf(m, __shfl_xor(m, 2, 64));
        m = fmaxf(m, __shfl_xor(m, 4, 64));
        m = fmaxf(m, __shfl_xor(m, 8, 64));
        float e0 = __expf(s0 - m), e1 = __expf(s1 - m);
        float sum = e0 + e1;
        sum += __shfl_xor(sum, 1, 64);
        sum += __shfl_xor(sum, 2, 64);
        sum += __shfl_xor(sum, 4, 64);
        sum += __shfl_xor(sum, 8, 64);
        rl[r] = 1.0f / sum;
        Pw[row * 32 + l16]      = (bf16)e0;
        Pw[row * 32 + 16 + l16] = (bf16)e1;
    }

    asm volatile("s_waitcnt vmcnt(0)" ::: "memory");
    bf16x8 pf = *(const bf16x8*)(Pw + l16 * 32 + quad * 8);
#pragma unroll
    for (int dt = 0; dt < 4; dt++) {
        bf16x8 vf;
#pragma unroll
        for (int jj = 0; jj < 8; jj++)
            vf[jj] = Vw[(quad * 8 + jj) * 64 + dt * 16 + l16];
        f32x4 ov = __builtin_amdgcn_mfma_f32_16x16x32_bf16(pf, vf, zero, 0, 0, 0);
#pragma unroll
        for (int r = 0; r < 4; r++) {
            const int row = quad * 4 + r;
            o[(size_t)(b * SS + q0 + row) * DD + h * HDD + dt * 16 + l16] =
                (bf16)(ov[r] * rl[r]);
        }
    }
}

// ---------------- launch ----------------
extern "C" void kernel_launch(void* const* d_in, const int* in_sizes, int n_in,
                              void* d_out, int out_size, void* d_ws, size_t ws_size,
                              hipStream_t stream)
{
    (void)in_sizes; (void)n_in; (void)out_size; (void)ws_size;
    const float* x    = (const float*)d_in[0];
    const float* ln1g = (const float*)d_in[1];
    const float* ln1b = (const float*)d_in[2];
    const float* Wqkv = (const float*)d_in[3];
    const float* bqkv = (const float*)d_in[4];
    const float* Wout = (const float*)d_in[5];
    const float* bout = (const float*)d_in[6];
    const float* ln2g = (const float*)d_in[7];
    const float* ln2b = (const float*)d_in[8];
    const float* W1   = (const float*)d_in[9];
    const float* b1   = (const float*)d_in[10];
    const float* W2   = (const float*)d_in[11];
    const float* b2   = (const float*)d_in[12];

    // Workspace (56 MiB peak):
    //   [0,16M)  W region. Phase A: Wqkv_bf @0..6M, Wout_bf @6..8M.
    //            Phase B: W1_bf @0..8M, W2_bf @8..16M (conv after out-proj).
    //   [16,48M) P region. Phase A: qkv bf16 24 MiB. Phase B: h1 bf16 32 MiB.
    //   [48,56M) H region: h (LN1 out) -> o (attn out) -> xn (LN2 out), serially.
    //   x1 fp32 lives in d_out; MLP2 split-K atomically accumulates in place.
    const size_t MB = (size_t)1 << 20;
    char* ws = (char*)d_ws;
    bf16* wqkv_bf = (bf16*)(ws);
    bf16* wout_bf = (bf16*)(ws + 6 * MB);
    bf16* w1_bf   = (bf16*)(ws);
    bf16* w2_bf   = (bf16*)(ws + 8 * MB);
    bf16* qkv     = (bf16*)(ws + 16 * MB);
    bf16* h1      = (bf16*)(ws + 16 * MB);
    bf16* hbuf    = (bf16*)(ws + 48 * MB);   // h, then o, then xn
    float* x1     = (float*)d_out;

    const dim3 blk(256);

    // Phase A: weights for QKV + out-proj
    conv_kernel<<<(3 * DD * DD / 8) / 256, blk, 0, stream>>>(Wqkv, wqkv_bf, 3 * DD * DD / 8);
    conv_kernel<<<(DD * DD / 8) / 256, blk, 0, stream>>>(Wout, wout_bf, DD * DD / 8);
    // h = LN1(x)
    ln_kernel<<<NTOK, blk, 0, stream>>>(x, ln1g, ln1b, hbuf);
    // qkv = h @ Wqkv^T + bqkv           (M=4096, N=3072, K=1024; 768 blocks = 3/CU)
    gemm_glds<128, 0, 0, 0><<<dim3(24, 32), blk, 0, stream>>>(
        hbuf, wqkv_bf, bqkv, nullptr, qkv, 3 * DD, DD);
    // o = attention(qkv)  (o overwrites h — h dead)
    attn_kernel<<<BB * HH * (SS / 16) / 4, blk, 0, stream>>>(qkv, hbuf);
    // x1 = x + o @ Wout^T + bout        (fp32 into d_out; M=4096, N=1024, K=1024)
    gemm_glds<64, 0, 2, 1><<<dim3(8, 64), blk, 0, stream>>>(
        hbuf, wout_bf, bout, x, x1, DD, DD);

    // Phase B: weights for MLP
    conv_kernel<<<(DFFD * DD / 8) / 256, blk, 0, stream>>>(W1, w1_bf, DFFD * DD / 8);
    conv_kernel<<<(DFFD * DD / 8) / 256, blk, 0, stream>>>(W2, w2_bf, DFFD * DD / 8);
    // xn = LN2(x1)   (xn overwrites o — o dead)
    ln_kernel<<<NTOK, blk, 0, stream>>>(x1, ln2g, ln2b, hbuf);
    // h1 = gelu(xn @ W1^T + b1)         (M=4096, N=4096, K=1024; 1024 blocks = 4/CU)
    gemm_glds<128, 1, 0, 0><<<dim3(32, 32), blk, 0, stream>>>(
        hbuf, w1_bf, b1, nullptr, h1, DFFD, DD);
    // out = x1 + h1 @ W2^T + b2         (split-K=2, TM=128: 512 blocks = 2/CU;
    //   8.4M atomics into pre-primed x1 in d_out)
    gemm_glds<128, 0, 3, 1><<<dim3(8, 32, 2), blk, 0, stream>>>(
        h1, w2_bf, b2, nullptr, x1, DD, DFFD);
}

// Round 10
// 299.425 us; speedup vs baseline: 1.0555x; 1.0039x over previous
//
#include <hip/hip_runtime.h>
#include <hip/hip_bf16.h>
#include <cmath>

typedef __bf16 bf16;
typedef __bf16 bf16x4 __attribute__((ext_vector_type(4)));
typedef __bf16 bf16x8 __attribute__((ext_vector_type(8)));
typedef float f32x4 __attribute__((ext_vector_type(4)));

#define BB 2
#define SS 2048
#define DD 1024
#define HH 16
#define WW 16
#define HDD 64
#define DFFD 4096
#define NTOK (BB*SS)

// gelu(x) = x * sigmoid(2*sqrt(2/pi)*(x+0.044715x^3))  == tanh-approx gelu
__device__ __forceinline__ float gelu_f(float x) {
    const float k = 1.5957691216057308f;  // 2*sqrt(2/pi)
    float u = k * (x + 0.044715f * x * x * x);
    return x / (1.0f + __expf(-u));
}

// ---- async global->LDS 16B/lane. LDS dest = wave-uniform base; HW adds lane*16. ----
__device__ __forceinline__ void glds16(const bf16* g, const bf16* l) {
    __builtin_amdgcn_global_load_lds(
        (const __attribute__((address_space(1))) void*)(uintptr_t)(const void*)g,
        (__attribute__((address_space(3))) void*)(unsigned)(uintptr_t)(const void*)l,
        16, 0, 0);
}

// ---------------- fp32 -> bf16 convert, two sources in one launch ----------------
__global__ __launch_bounds__(256) void conv2_kernel(
    const float* __restrict__ s0, bf16* __restrict__ d0, int n0,
    const float* __restrict__ s1, bf16* __restrict__ d1, int n1)
{
    int i = blockIdx.x * 256 + threadIdx.x;
    const float* src; bf16* dst; int idx;
    if (i < n0) { src = s0; dst = d0; idx = i; }
    else        { idx = i - n0; if (idx >= n1) return; src = s1; dst = d1; }
    f32x4 a = *(const f32x4*)(src + (size_t)idx * 8);
    f32x4 b = *(const f32x4*)(src + (size_t)idx * 8 + 4);
    bf16x8 v;
#pragma unroll
    for (int j = 0; j < 4; j++) { v[j] = (bf16)a[j]; v[4 + j] = (bf16)b[j]; }
    *(bf16x8*)(dst + (size_t)idx * 8) = v;
}

// ---------------- fused LayerNorm: fp32 row -> bf16 row, one block/row ----------------
__global__ __launch_bounds__(256) void ln_kernel(
    const float* __restrict__ x, const float* __restrict__ g, const float* __restrict__ b,
    bf16* __restrict__ out)
{
    const int row = blockIdx.x, t = threadIdx.x;
    f32x4 v = *(const f32x4*)(x + (size_t)row * DD + t * 4);
    float s  = v[0] + v[1] + v[2] + v[3];
    float s2 = v[0]*v[0] + v[1]*v[1] + v[2]*v[2] + v[3]*v[3];
#pragma unroll
    for (int off = 32; off >= 1; off >>= 1) {
        s  += __shfl_xor(s,  off, 64);
        s2 += __shfl_xor(s2, off, 64);
    }
    __shared__ float red[8];
    const int wave = t >> 6;
    if ((t & 63) == 0) { red[wave] = s; red[4 + wave] = s2; }
    __syncthreads();
    float ts  = red[0] + red[1] + red[2] + red[3];
    float ts2 = red[4] + red[5] + red[6] + red[7];
    float mean = ts * (1.0f / DD);
    float var  = ts2 * (1.0f / DD) - mean * mean;
    float rstd = rsqrtf(var + 1e-5f);
    f32x4 gv = *(const f32x4*)(g + t * 4);
    f32x4 bv = *(const f32x4*)(b + t * 4);
    bf16x4 o;
#pragma unroll
    for (int i = 0; i < 4; i++) o[i] = (bf16)((v[i] - mean) * rstd * gv[i] + bv[i]);
    *(bf16x4*)(out + (size_t)row * DD + t * 4) = o;
}

// ======== bf16 MFMA GEMM: ring-3 counted-vmcnt pipeline + T1 XCD swizzle ========
// C[M,N] = A[M,K] @ W[N,K]^T + bias.  256 thr, TM=128 (waves 2x2, 4x4 frags) or
// TM=64 (1x4, 4x2). BN=128, BK=32.
// k-loop (R9): iter t: vmcnt(L) -> s_barrier -> stage(t+2) -> ds_read frags -> MFMA.
//   NO explicit lgkmcnt(0)/sched_barrier before the MFMAs (R8 post-mortem: the
//   ds_reads are plain loads, so the compiler emits fine-grained lgkmcnt(4/3/1/0)
//   letting the first MFMAs start as soon as THEIR frags land; the explicit full
//   drain + order pin was serializing the iter — m141's order-pinning regression).
//   Correctness: slot-t visibility = vmcnt(L)+barrier; ds_read->MFMA = register dep;
//   WAR on slot (t-1) holds since iter t-1's MFMAs (which drained those reads)
//   precede barrier(t) in every wave, and glds16 can't hoist across s_barrier.
//   vmcnt: stage-first keeps the invariant (only tile t+1's L loads + just-issued
//   t+2's in flight; vmcnt(L) at iter top forces tile t complete). Tail vmcnt(0).
// T1 XCD swizzle (R8, measured FETCH 135.8->49.2 MB on MLP1): swz=(bid&7)*cpx+(bid>>3)
//   gives each XCD a contiguous tile range. Requires nbxy%8==0 (768/1024/512/256).
// T2 swizzle (R4-verified 0-conflict): source col-group qsw pre-inverts; read slot
//   rsl=(quad^((l16>>1)&3))*8.
// RESID: 2=add fp32 resid (may alias Cout, same elem same thread). 3=split-K over
// gridDim.z, unsafeAtomicAdd into pre-primed fp32 Cout, bias at z==0. ACT: 1=gelu.
template<int TM, int ACT, int RESID, int OUTF32>
__global__ __launch_bounds__(256) void gemm_glds(
    const bf16* __restrict__ A, const bf16* __restrict__ Bw,
    const float* __restrict__ bias,
    const float* resid, void* __restrict__ Cout, int N, int K)
{
    constexpr int MI = 4;
    constexpr int NJ = (TM == 128) ? 4 : 2;
    __shared__ __align__(16) bf16 As[3 * TM * 32];
    __shared__ __align__(16) bf16 Bs[3 * 128 * 32];
    const int t = threadIdx.x;
    // T1: bijective XCD swizzle over linearized xy grid
    const int nbxy = gridDim.x * gridDim.y;
    const int bid  = blockIdx.y * gridDim.x + blockIdx.x;
    const int cpx  = nbxy >> 3;
    const int swz  = (bid & 7) * cpx + (bid >> 3);
    const int m0 = (swz / gridDim.x) * TM;
    const int n0 = (swz % gridDim.x) * 128;
    const int lane = t & 63, w = t >> 6;
    const int wm = (TM == 128) ? (w & 1) * 64 : 0;
    const int wn = (TM == 128) ? (w >> 1) * 64 : w * 32;
    const int quad = lane >> 4, l16 = lane & 15;
    const int srow = t >> 2;                       // 4 lanes/row, 16 B each
    const int qsw  = (t & 3) ^ ((srow >> 1) & 3);  // T2 inverse perm on global source

    const bf16* Ag = A  + (size_t)(m0 + srow) * K + qsw * 8;
    const bf16* Bg = Bw + (size_t)(n0 + srow) * K + qsw * 8;

    int k_lo = 0, k_hi = K;
    if (RESID == 3) {                 // split-K: this block handles one K-slice
        const int ks = K / gridDim.z;
        k_lo = blockIdx.z * ks;
        k_hi = k_lo + ks;
    }

    auto stage = [&](int buf, int k0) {
        const bf16* AsW = As + buf * (TM * 32) + w * 512;
        const bf16* BsW = Bs + buf * (128 * 32) + w * 512;
        glds16(Ag + k0, AsW);
        if (TM == 128) glds16(Ag + (size_t)64 * K + k0, AsW + 2048);
        glds16(Bg + k0, BsW);
        glds16(Bg + (size_t)64 * K + k0, BsW + 2048);
    };

    const f32x4 zero = {0.f, 0.f, 0.f, 0.f};
    f32x4 acc[MI][NJ];
#pragma unroll
    for (int i = 0; i < MI; i++)
#pragma unroll
        for (int j = 0; j < NJ; j++) acc[i][j] = zero;

    const int nsteps = (k_hi - k_lo) >> 5;
    stage(0, k_lo);
    if (nsteps > 1) stage(1, k_lo + 32);

    const int rsl = (quad ^ ((l16 >> 1) & 3)) * 8;   // T2 read-side slot (bf16 off)
    int cur = 0, nxt2 = 2;                            // step%3, (step+2)%3
    for (int step = 0; step < nsteps; ++step) {
        // counted vmcnt: tile t+1's L loads may stay in flight; tile t's landed.
        if (step < nsteps - 1) {
            if (TM == 128) asm volatile("s_waitcnt vmcnt(4)" ::: "memory");
            else           asm volatile("s_waitcnt vmcnt(3)" ::: "memory");
        } else {
            asm volatile("s_waitcnt vmcnt(0)" ::: "memory");
        }
        __builtin_amdgcn_s_barrier();
        if (step + 2 < nsteps) stage(nxt2, k_lo + ((step + 2) << 5));
        const bf16* Ab = As + cur * (TM * 32);
        const bf16* Bb = Bs + cur * (128 * 32);
        bf16x8 af[MI], bfr[NJ];
#pragma unroll
        for (int i = 0; i < MI; i++)
            af[i] = *(const bf16x8*)(Ab + (wm + i * 16 + l16) * 32 + rsl);
#pragma unroll
        for (int j = 0; j < NJ; j++)
            bfr[j] = *(const bf16x8*)(Bb + (wn + j * 16 + l16) * 32 + rsl);
        // no lgkmcnt(0)/sched_barrier: compiler emits fine-grained lgkm waits,
        // first MFMAs overlap the remaining ds_read latency.
#pragma unroll
        for (int i = 0; i < MI; i++)
#pragma unroll
            for (int j = 0; j < NJ; j++)
                acc[i][j] = __builtin_amdgcn_mfma_f32_16x16x32_bf16(af[i], bfr[j], acc[i][j], 0, 0, 0);
        cur  = (cur  + 1 == 3) ? 0 : cur  + 1;
        nxt2 = (nxt2 + 1 == 3) ? 0 : nxt2 + 1;
    }

#pragma unroll
    for (int i = 0; i < MI; i++) {
#pragma unroll
        for (int j = 0; j < NJ; j++) {
            int col = n0 + wn + j * 16 + l16;
            float bv = bias[col];
            if (RESID == 3 && blockIdx.z != 0) bv = 0.0f;
#pragma unroll
            for (int r = 0; r < 4; r++) {
                int row = m0 + wm + i * 16 + quad * 4 + r;
                float val = acc[i][j][r] + bv;
                if (ACT == 1) val = gelu_f(val);
                size_t idx = (size_t)row * N + col;
                if (RESID == 2) val += resid[idx];
                if (RESID == 3) {
                    unsafeAtomicAdd(&((float*)Cout)[idx], val);   // HW global_atomic_add_f32
                } else if (OUTF32) {
                    ((float*)Cout)[idx] = val;
                } else {
                    ((bf16*)Cout)[idx] = (bf16)val;
                }
            }
        }
    }
}

// ---------------- Sliding-window causal attention, MFMA-tiled ----------------
// One wave per (b, h, 16-query block); window W=16 -> two 16-key tiles.
// QK^T: 4 MFMAs, A/B frags direct from global. Softmax: 16-lane butterfly.
// P via 1KB wave-private LDS; V staged per-wave via glds16, consumed transposed.
__global__ __launch_bounds__(256) void attn_kernel(
    const bf16* __restrict__ qkv, bf16* __restrict__ o)
{
    __shared__ __align__(16) bf16 Vlds[4][32 * 64];
    __shared__ __align__(16) bf16 Plds[4][16 * 32];
    const int t = threadIdx.x;
    const int w = t >> 6, lane = t & 63;
    const int quad = lane >> 4, l16 = lane & 15;
    const int gw = blockIdx.x * 4 + w;
    const int qb = gw & 127;
    const int h  = (gw >> 7) & (HH - 1);
    const int b  = gw >> 11;
    const int q0 = qb << 4;
    const size_t rs = 3 * DD;
    const bf16* Qb = qkv + (size_t)b * SS * rs + h * HDD;
    const bf16* Kb = Qb + DD;
    const bf16* Vb = Qb + 2 * DD;
    bf16* Vw = Vlds[w];
    bf16* Pw = Plds[w];

    {
        const int sub = lane >> 3;
        const int dc  = (lane & 7) * 8;
#pragma unroll
        for (int c = 0; c < 4; c++) {
            int key = q0 - 16 + c * 8 + sub;
            if (key < 0) key = 0;
            glds16(Vb + (size_t)key * rs + dc, Vw + c * 512);
        }
    }

    const int qrow = q0 + l16;
    int kr0 = q0 - 16 + l16; if (kr0 < 0) kr0 = 0;
    bf16x8 qf0  = *(const bf16x8*)(Qb + (size_t)qrow * rs + quad * 8);
    bf16x8 qf1  = *(const bf16x8*)(Qb + (size_t)qrow * rs + 32 + quad * 8);
    bf16x8 kf0a = *(const bf16x8*)(Kb + (size_t)kr0  * rs + quad * 8);
    bf16x8 kf0b = *(const bf16x8*)(Kb + (size_t)kr0  * rs + 32 + quad * 8);
    bf16x8 kf1a = *(const bf16x8*)(Kb + (size_t)qrow * rs + quad * 8);
    bf16x8 kf1b = *(const bf16x8*)(Kb + (size_t)qrow * rs + 32 + quad * 8);

    const f32x4 zero = {0.f, 0.f, 0.f, 0.f};
    f32x4 acc0 = __builtin_amdgcn_mfma_f32_16x16x32_bf16(qf0, kf0a, zero, 0, 0, 0);
    acc0 = __builtin_amdgcn_mfma_f32_16x16x32_bf16(qf1, kf0b, acc0, 0, 0, 0);
    f32x4 acc1 = __builtin_amdgcn_mfma_f32_16x16x32_bf16(qf0, kf1a, zero, 0, 0, 0);
    acc1 = __builtin_amdgcn_mfma_f32_16x16x32_bf16(qf1, kf1b, acc1, 0, 0, 0);

    float rl[4];
#pragma unroll
    for (int r = 0; r < 4; r++) {
        const int row = quad * 4 + r;
        float s0 = (l16 > row && q0 - 16 + l16 >= 0) ? acc0[r] * 0.125f : -1e30f;
        float s1 = (l16 <= row)                      ? acc1[r] * 0.125f : -1e30f;
        float m = fmaxf(s0, s1);
        m = fmaxf(m, __shfl_xor(m, 1, 64));
        m = fmaxf(m, __shfl_xor(m, 2, 64));
        m = fmaxf(m, __shfl_xor(m, 4, 64));
        m = fmaxf(m, __shfl_xor(m, 8, 64));
        float e0 = __expf(s0 - m), e1 = __expf(s1 - m);
        float sum = e0 + e1;
        sum += __shfl_xor(sum, 1, 64);
        sum += __shfl_xor(sum, 2, 64);
        sum += __shfl_xor(sum, 4, 64);
        sum += __shfl_xor(sum, 8, 64);
        rl[r] = 1.0f / sum;
        Pw[row * 32 + l16]      = (bf16)e0;
        Pw[row * 32 + 16 + l16] = (bf16)e1;
    }

    asm volatile("s_waitcnt vmcnt(0)" ::: "memory");
    bf16x8 pf = *(const bf16x8*)(Pw + l16 * 32 + quad * 8);
#pragma unroll
    for (int dt = 0; dt < 4; dt++) {
        bf16x8 vf;
#pragma unroll
        for (int jj = 0; jj < 8; jj++)
            vf[jj] = Vw[(quad * 8 + jj) * 64 + dt * 16 + l16];
        f32x4 ov = __builtin_amdgcn_mfma_f32_16x16x32_bf16(pf, vf, zero, 0, 0, 0);
#pragma unroll
        for (int r = 0; r < 4; r++) {
            const int row = quad * 4 + r;
            o[(size_t)(b * SS + q0 + row) * DD + h * HDD + dt * 16 + l16] =
                (bf16)(ov[r] * rl[r]);
        }
    }
}

// ---------------- launch ----------------
extern "C" void kernel_launch(void* const* d_in, const int* in_sizes, int n_in,
                              void* d_out, int out_size, void* d_ws, size_t ws_size,
                              hipStream_t stream)
{
    (void)in_sizes; (void)n_in; (void)out_size; (void)ws_size;
    const float* x    = (const float*)d_in[0];
    const float* ln1g = (const float*)d_in[1];
    const float* ln1b = (const float*)d_in[2];
    const float* Wqkv = (const float*)d_in[3];
    const float* bqkv = (const float*)d_in[4];
    const float* Wout = (const float*)d_in[5];
    const float* bout = (const float*)d_in[6];
    const float* ln2g = (const float*)d_in[7];
    const float* ln2b = (const float*)d_in[8];
    const float* W1   = (const float*)d_in[9];
    const float* b1   = (const float*)d_in[10];
    const float* W2   = (const float*)d_in[11];
    const float* b2   = (const float*)d_in[12];

    // Workspace (56 MiB peak):
    //   [0,16M)  W region. Phase A: Wqkv_bf @0..6M, Wout_bf @6..8M.
    //            Phase B: W1_bf @0..8M, W2_bf @8..16M (conv after out-proj).
    //   [16,48M) P region. Phase A: qkv bf16 24 MiB. Phase B: h1 bf16 32 MiB.
    //   [48,56M) H region: h (LN1 out) -> o (attn out) -> xn (LN2 out), serially.
    //   x1 fp32 lives in d_out; MLP2 split-K atomically accumulates in place.
    const size_t MB = (size_t)1 << 20;
    char* ws = (char*)d_ws;
    bf16* wqkv_bf = (bf16*)(ws);
    bf16* wout_bf = (bf16*)(ws + 6 * MB);
    bf16* w1_bf   = (bf16*)(ws);
    bf16* w2_bf   = (bf16*)(ws + 8 * MB);
    bf16* qkv     = (bf16*)(ws + 16 * MB);
    bf16* h1      = (bf16*)(ws + 16 * MB);
    bf16* hbuf    = (bf16*)(ws + 48 * MB);   // h, then o, then xn
    float* x1     = (float*)d_out;

    const dim3 blk(256);

    // Phase A: weights for QKV + out-proj (one dual-source conv launch)
    {
        const int n0 = 3 * DD * DD / 8, n1 = DD * DD / 8;
        conv2_kernel<<<(n0 + n1 + 255) / 256, blk, 0, stream>>>(
            Wqkv, wqkv_bf, n0, Wout, wout_bf, n1);
    }
    // h = LN1(x)
    ln_kernel<<<NTOK, blk, 0, stream>>>(x, ln1g, ln1b, hbuf);
    // qkv = h @ Wqkv^T + bqkv           (M=4096, N=3072, K=1024; 768 blocks = 3/CU)
    gemm_glds<128, 0, 0, 0><<<dim3(24, 32), blk, 0, stream>>>(
        hbuf, wqkv_bf, bqkv, nullptr, qkv, 3 * DD, DD);
    // o = attention(qkv)  (o overwrites h — h dead)
    attn_kernel<<<BB * HH * (SS / 16) / 4, blk, 0, stream>>>(qkv, hbuf);
    // x1 = x + o @ Wout^T + bout        (fp32 into d_out; M=4096, N=1024, K=1024)
    gemm_glds<64, 0, 2, 1><<<dim3(8, 64), blk, 0, stream>>>(
        hbuf, wout_bf, bout, x, x1, DD, DD);

    // Phase B: weights for MLP (one dual-source conv launch)
    {
        const int n0 = DFFD * DD / 8, n1 = DFFD * DD / 8;
        conv2_kernel<<<(n0 + n1 + 255) / 256, blk, 0, stream>>>(
            W1, w1_bf, n0, W2, w2_bf, n1);
    }
    // xn = LN2(x1)   (xn overwrites o — o dead)
    ln_kernel<<<NTOK, blk, 0, stream>>>(x1, ln2g, ln2b, hbuf);
    // h1 = gelu(xn @ W1^T + b1)         (M=4096, N=4096, K=1024; 1024 blocks = 4/CU)
    gemm_glds<128, 1, 0, 0><<<dim3(32, 32), blk, 0, stream>>>(
        hbuf, w1_bf, b1, nullptr, h1, DFFD, DD);
    // out = x1 + h1 @ W2^T + b2         (split-K=2, TM=128: 512 blocks = 2/CU;
    //   8.4M atomics into pre-primed x1 in d_out)
    gemm_glds<128, 0, 3, 1><<<dim3(8, 32, 2), blk, 0, stream>>>(
        h1, w2_bf, b2, nullptr, x1, DD, DFFD);
}

// Round 11
// 298.412 us; speedup vs baseline: 1.0591x; 1.0034x over previous
//
#include <hip/hip_runtime.h>
#include <hip/hip_bf16.h>
#include <cmath>

typedef __bf16 bf16;
typedef __bf16 bf16x4 __attribute__((ext_vector_type(4)));
typedef __bf16 bf16x8 __attribute__((ext_vector_type(8)));
typedef float f32x4 __attribute__((ext_vector_type(4)));

#define BB 2
#define SS 2048
#define DD 1024
#define HH 16
#define WW 16
#define HDD 64
#define DFFD 4096
#define NTOK (BB*SS)

// gelu(x) = x * sigmoid(2*sqrt(2/pi)*(x+0.044715x^3))  == tanh-approx gelu
__device__ __forceinline__ float gelu_f(float x) {
    const float k = 1.5957691216057308f;  // 2*sqrt(2/pi)
    float u = k * (x + 0.044715f * x * x * x);
    return x / (1.0f + __expf(-u));
}

// ---- async global->LDS 16B/lane. LDS dest = wave-uniform base; HW adds lane*16. ----
__device__ __forceinline__ void glds16(const bf16* g, const bf16* l) {
    __builtin_amdgcn_global_load_lds(
        (const __attribute__((address_space(1))) void*)(uintptr_t)(const void*)g,
        (__attribute__((address_space(3))) void*)(unsigned)(uintptr_t)(const void*)l,
        16, 0, 0);
}

// ======== fused: fp32->bf16 weight convert (2 sources) + LayerNorm, one launch ========
// Blocks [0, ncb): conv path over s0 (n0 vec8s) then s1 (n1 vec8s).
// Blocks [ncb, ncb+nln): LN path, one block per row of xin -> lnout (bf16).
// The two ops are independent; merging removes one launch + serialization gap.
__global__ __launch_bounds__(256) void conv2ln_kernel(
    const float* __restrict__ s0, bf16* __restrict__ d0, int n0,
    const float* __restrict__ s1, bf16* __restrict__ d1, int n1, int ncb,
    const float* __restrict__ xin, const float* __restrict__ g,
    const float* __restrict__ b, bf16* __restrict__ lnout)
{
    const int t = threadIdx.x;
    if ((int)blockIdx.x < ncb) {
        int i = blockIdx.x * 256 + t;
        const float* src; bf16* dst; int idx;
        if (i < n0) { src = s0; dst = d0; idx = i; }
        else        { idx = i - n0; if (idx >= n1) return; src = s1; dst = d1; }
        f32x4 a = *(const f32x4*)(src + (size_t)idx * 8);
        f32x4 c = *(const f32x4*)(src + (size_t)idx * 8 + 4);
        bf16x8 v;
#pragma unroll
        for (int j = 0; j < 4; j++) { v[j] = (bf16)a[j]; v[4 + j] = (bf16)c[j]; }
        *(bf16x8*)(dst + (size_t)idx * 8) = v;
        return;
    }
    // ---- LN path ----
    const int row = blockIdx.x - ncb;
    f32x4 v = *(const f32x4*)(xin + (size_t)row * DD + t * 4);
    float s  = v[0] + v[1] + v[2] + v[3];
    float s2 = v[0]*v[0] + v[1]*v[1] + v[2]*v[2] + v[3]*v[3];
#pragma unroll
    for (int off = 32; off >= 1; off >>= 1) {
        s  += __shfl_xor(s,  off, 64);
        s2 += __shfl_xor(s2, off, 64);
    }
    __shared__ float red[8];
    const int wave = t >> 6;
    if ((t & 63) == 0) { red[wave] = s; red[4 + wave] = s2; }
    __syncthreads();
    float ts  = red[0] + red[1] + red[2] + red[3];
    float ts2 = red[4] + red[5] + red[6] + red[7];
    float mean = ts * (1.0f / DD);
    float var  = ts2 * (1.0f / DD) - mean * mean;
    float rstd = rsqrtf(var + 1e-5f);
    f32x4 gv = *(const f32x4*)(g + t * 4);
    f32x4 bv = *(const f32x4*)(b + t * 4);
    bf16x4 o;
#pragma unroll
    for (int i = 0; i < 4; i++) o[i] = (bf16)((v[i] - mean) * rstd * gv[i] + bv[i]);
    *(bf16x4*)(lnout + (size_t)row * DD + t * 4) = o;
}

// ======== bf16 MFMA GEMM: ring-4 depth-3 counted-vmcnt pipeline + T1 XCD swizzle ====
// C[M,N] = A[M,K] @ W[N,K]^T + bias.  256 thr, TM=128 (waves 2x2, 4x4 frags) or
// TM=64 (1x4, 4x2). BN=128, BK=32.
// R10: ring-3/depth-2 under-covered HBM-miss latency (~900 cyc, m126) — loads were
// issued only ~2 iters (~400-800 cyc) before their vmcnt. Ring-4/depth-3: prologue
// stages 0,1,2; iter t computes slot t&3, stages t+3 -> ~3 iters of cover.
//   vmcnt: steady-state outstanding = stages(t+1,t+2) = 2L -> vmcnt(2L) ensures
//   tile t landed (L=4 TM=128, 3 TM=64). Tail: t==NK-2 -> vmcnt(L); t==NK-1 -> 0.
//   WAR: stage(t+3) overwrites slot (t-1)&3, whose reads were lgkm-waited before
//   iter t-1's MFMAs issued in every wave, hence before all crossed barrier(t).
//   LDS 64 KB (TM=128) -> 2 blocks/CU: trades TLP for pipeline depth (m201 runs
//   1 block/CU fine at depth 3; m132's regression was bigger STEPS, not depth).
// No explicit lgkmcnt/sched_barrier before MFMAs (R9: compiler emits fine-grained
// lgkm waits; full drain serialized the iter).
// T1 XCD swizzle (R8, FETCH 135.8->49.2 MB): swz=(bid&7)*cpx+(bid>>3), nbxy%8==0.
// T2 swizzle (R4, 0 conflicts): source col-group qsw pre-inverts; read slot rsl.
// RESID: 2=add fp32 resid (may alias Cout, same elem same thread). 3=split-K over
// gridDim.z, unsafeAtomicAdd into pre-primed fp32 Cout, bias at z==0. ACT: 1=gelu.
template<int TM, int ACT, int RESID, int OUTF32>
__global__ __launch_bounds__(256) void gemm_glds(
    const bf16* __restrict__ A, const bf16* __restrict__ Bw,
    const float* __restrict__ bias,
    const float* resid, void* __restrict__ Cout, int N, int K)
{
    constexpr int MI = 4;
    constexpr int NJ = (TM == 128) ? 4 : 2;
    __shared__ __align__(16) bf16 As[4 * TM * 32];
    __shared__ __align__(16) bf16 Bs[4 * 128 * 32];
    const int t = threadIdx.x;
    // T1: bijective XCD swizzle over linearized xy grid
    const int nbxy = gridDim.x * gridDim.y;
    const int bid  = blockIdx.y * gridDim.x + blockIdx.x;
    const int cpx  = nbxy >> 3;
    const int swz  = (bid & 7) * cpx + (bid >> 3);
    const int m0 = (swz / gridDim.x) * TM;
    const int n0 = (swz % gridDim.x) * 128;
    const int lane = t & 63, w = t >> 6;
    const int wm = (TM == 128) ? (w & 1) * 64 : 0;
    const int wn = (TM == 128) ? (w >> 1) * 64 : w * 32;
    const int quad = lane >> 4, l16 = lane & 15;
    const int srow = t >> 2;                       // 4 lanes/row, 16 B each
    const int qsw  = (t & 3) ^ ((srow >> 1) & 3);  // T2 inverse perm on global source

    const bf16* Ag = A  + (size_t)(m0 + srow) * K + qsw * 8;
    const bf16* Bg = Bw + (size_t)(n0 + srow) * K + qsw * 8;

    int k_lo = 0, k_hi = K;
    if (RESID == 3) {                 // split-K: this block handles one K-slice
        const int ks = K / gridDim.z;
        k_lo = blockIdx.z * ks;
        k_hi = k_lo + ks;
    }

    auto stage = [&](int buf, int k0) {
        const bf16* AsW = As + buf * (TM * 32) + w * 512;
        const bf16* BsW = Bs + buf * (128 * 32) + w * 512;
        glds16(Ag + k0, AsW);
        if (TM == 128) glds16(Ag + (size_t)64 * K + k0, AsW + 2048);
        glds16(Bg + k0, BsW);
        glds16(Bg + (size_t)64 * K + k0, BsW + 2048);
    };

    const f32x4 zero = {0.f, 0.f, 0.f, 0.f};
    f32x4 acc[MI][NJ];
#pragma unroll
    for (int i = 0; i < MI; i++)
#pragma unroll
        for (int j = 0; j < NJ; j++) acc[i][j] = zero;

    const int nsteps = (k_hi - k_lo) >> 5;
    stage(0, k_lo);
    if (nsteps > 1) stage(1, k_lo + 32);
    if (nsteps > 2) stage(2, k_lo + 64);

    const int rsl = (quad ^ ((l16 >> 1) & 3)) * 8;   // T2 read-side slot (bf16 off)
    for (int step = 0; step < nsteps; ++step) {
        // counted vmcnt: stages t+1,t+2 (2L) may stay in flight; tile t's landed.
        if (step < nsteps - 2) {
            if (TM == 128) asm volatile("s_waitcnt vmcnt(8)" ::: "memory");
            else           asm volatile("s_waitcnt vmcnt(6)" ::: "memory");
        } else if (step == nsteps - 2) {
            if (TM == 128) asm volatile("s_waitcnt vmcnt(4)" ::: "memory");
            else           asm volatile("s_waitcnt vmcnt(3)" ::: "memory");
        } else {
            asm volatile("s_waitcnt vmcnt(0)" ::: "memory");
        }
        __builtin_amdgcn_s_barrier();
        if (step + 3 < nsteps) stage((step + 3) & 3, k_lo + ((step + 3) << 5));
        const bf16* Ab = As + (step & 3) * (TM * 32);
        const bf16* Bb = Bs + (step & 3) * (128 * 32);
        bf16x8 af[MI], bfr[NJ];
#pragma unroll
        for (int i = 0; i < MI; i++)
            af[i] = *(const bf16x8*)(Ab + (wm + i * 16 + l16) * 32 + rsl);
#pragma unroll
        for (int j = 0; j < NJ; j++)
            bfr[j] = *(const bf16x8*)(Bb + (wn + j * 16 + l16) * 32 + rsl);
        // compiler emits fine-grained lgkm waits; first MFMAs overlap ds_read latency
#pragma unroll
        for (int i = 0; i < MI; i++)
#pragma unroll
            for (int j = 0; j < NJ; j++)
                acc[i][j] = __builtin_amdgcn_mfma_f32_16x16x32_bf16(af[i], bfr[j], acc[i][j], 0, 0, 0);
    }

#pragma unroll
    for (int i = 0; i < MI; i++) {
#pragma unroll
        for (int j = 0; j < NJ; j++) {
            int col = n0 + wn + j * 16 + l16;
            float bv = bias[col];
            if (RESID == 3 && blockIdx.z != 0) bv = 0.0f;
#pragma unroll
            for (int r = 0; r < 4; r++) {
                int row = m0 + wm + i * 16 + quad * 4 + r;
                float val = acc[i][j][r] + bv;
                if (ACT == 1) val = gelu_f(val);
                size_t idx = (size_t)row * N + col;
                if (RESID == 2) val += resid[idx];
                if (RESID == 3) {
                    unsafeAtomicAdd(&((float*)Cout)[idx], val);   // HW global_atomic_add_f32
                } else if (OUTF32) {
                    ((float*)Cout)[idx] = val;
                } else {
                    ((bf16*)Cout)[idx] = (bf16)val;
                }
            }
        }
    }
}

// ---------------- Sliding-window causal attention, MFMA-tiled ----------------
// One wave per (b, h, 16-query block); window W=16 -> two 16-key tiles.
// QK^T: 4 MFMAs, A/B frags direct from global. Softmax: 16-lane butterfly.
// P via 1KB wave-private LDS; V staged per-wave via glds16, consumed transposed.
__global__ __launch_bounds__(256) void attn_kernel(
    const bf16* __restrict__ qkv, bf16* __restrict__ o)
{
    __shared__ __align__(16) bf16 Vlds[4][32 * 64];
    __shared__ __align__(16) bf16 Plds[4][16 * 32];
    const int t = threadIdx.x;
    const int w = t >> 6, lane = t & 63;
    const int quad = lane >> 4, l16 = lane & 15;
    const int gw = blockIdx.x * 4 + w;
    const int qb = gw & 127;
    const int h  = (gw >> 7) & (HH - 1);
    const int b  = gw >> 11;
    const int q0 = qb << 4;
    const size_t rs = 3 * DD;
    const bf16* Qb = qkv + (size_t)b * SS * rs + h * HDD;
    const bf16* Kb = Qb + DD;
    const bf16* Vb = Qb + 2 * DD;
    bf16* Vw = Vlds[w];
    bf16* Pw = Plds[w];

    {
        const int sub = lane >> 3;
        const int dc  = (lane & 7) * 8;
#pragma unroll
        for (int c = 0; c < 4; c++) {
            int key = q0 - 16 + c * 8 + sub;
            if (key < 0) key = 0;
            glds16(Vb + (size_t)key * rs + dc, Vw + c * 512);
        }
    }

    const int qrow = q0 + l16;
    int kr0 = q0 - 16 + l16; if (kr0 < 0) kr0 = 0;
    bf16x8 qf0  = *(const bf16x8*)(Qb + (size_t)qrow * rs + quad * 8);
    bf16x8 qf1  = *(const bf16x8*)(Qb + (size_t)qrow * rs + 32 + quad * 8);
    bf16x8 kf0a = *(const bf16x8*)(Kb + (size_t)kr0  * rs + quad * 8);
    bf16x8 kf0b = *(const bf16x8*)(Kb + (size_t)kr0  * rs + 32 + quad * 8);
    bf16x8 kf1a = *(const bf16x8*)(Kb + (size_t)qrow * rs + quad * 8);
    bf16x8 kf1b = *(const bf16x8*)(Kb + (size_t)qrow * rs + 32 + quad * 8);

    const f32x4 zero = {0.f, 0.f, 0.f, 0.f};
    f32x4 acc0 = __builtin_amdgcn_mfma_f32_16x16x32_bf16(qf0, kf0a, zero, 0, 0, 0);
    acc0 = __builtin_amdgcn_mfma_f32_16x16x32_bf16(qf1, kf0b, acc0, 0, 0, 0);
    f32x4 acc1 = __builtin_amdgcn_mfma_f32_16x16x32_bf16(qf0, kf1a, zero, 0, 0, 0);
    acc1 = __builtin_amdgcn_mfma_f32_16x16x32_bf16(qf1, kf1b, acc1, 0, 0, 0);

    float rl[4];
#pragma unroll
    for (int r = 0; r < 4; r++) {
        const int row = quad * 4 + r;
        float s0 = (l16 > row && q0 - 16 + l16 >= 0) ? acc0[r] * 0.125f : -1e30f;
        float s1 = (l16 <= row)                      ? acc1[r] * 0.125f : -1e30f;
        float m = fmaxf(s0, s1);
        m = fmaxf(m, __shfl_xor(m, 1, 64));
        m = fmaxf(m, __shfl_xor(m, 2, 64));
        m = fmaxf(m, __shfl_xor(m, 4, 64));
        m = fmaxf(m, __shfl_xor(m, 8, 64));
        float e0 = __expf(s0 - m), e1 = __expf(s1 - m);
        float sum = e0 + e1;
        sum += __shfl_xor(sum, 1, 64);
        sum += __shfl_xor(sum, 2, 64);
        sum += __shfl_xor(sum, 4, 64);
        sum += __shfl_xor(sum, 8, 64);
        rl[r] = 1.0f / sum;
        Pw[row * 32 + l16]      = (bf16)e0;
        Pw[row * 32 + 16 + l16] = (bf16)e1;
    }

    asm volatile("s_waitcnt vmcnt(0)" ::: "memory");
    bf16x8 pf = *(const bf16x8*)(Pw + l16 * 32 + quad * 8);
#pragma unroll
    for (int dt = 0; dt < 4; dt++) {
        bf16x8 vf;
#pragma unroll
        for (int jj = 0; jj < 8; jj++)
            vf[jj] = Vw[(quad * 8 + jj) * 64 + dt * 16 + l16];
        f32x4 ov = __builtin_amdgcn_mfma_f32_16x16x32_bf16(pf, vf, zero, 0, 0, 0);
#pragma unroll
        for (int r = 0; r < 4; r++) {
            const int row = quad * 4 + r;
            o[(size_t)(b * SS + q0 + row) * DD + h * HDD + dt * 16 + l16] =
                (bf16)(ov[r] * rl[r]);
        }
    }
}

// ---------------- launch ----------------
extern "C" void kernel_launch(void* const* d_in, const int* in_sizes, int n_in,
                              void* d_out, int out_size, void* d_ws, size_t ws_size,
                              hipStream_t stream)
{
    (void)in_sizes; (void)n_in; (void)out_size; (void)ws_size;
    const float* x    = (const float*)d_in[0];
    const float* ln1g = (const float*)d_in[1];
    const float* ln1b = (const float*)d_in[2];
    const float* Wqkv = (const float*)d_in[3];
    const float* bqkv = (const float*)d_in[4];
    const float* Wout = (const float*)d_in[5];
    const float* bout = (const float*)d_in[6];
    const float* ln2g = (const float*)d_in[7];
    const float* ln2b = (const float*)d_in[8];
    const float* W1   = (const float*)d_in[9];
    const float* b1   = (const float*)d_in[10];
    const float* W2   = (const float*)d_in[11];
    const float* b2   = (const float*)d_in[12];

    // Workspace (56 MiB peak):
    //   [0,16M)  W region. Phase A: Wqkv_bf @0..6M, Wout_bf @6..8M.
    //            Phase B: W1_bf @0..8M, W2_bf @8..16M (conv after out-proj).
    //   [16,48M) P region. Phase A: qkv bf16 24 MiB. Phase B: h1 bf16 32 MiB.
    //   [48,56M) H region: h (LN1 out) -> o (attn out) -> xn (LN2 out), serially.
    //   x1 fp32 lives in d_out; MLP2 split-K atomically accumulates in place.
    const size_t MB = (size_t)1 << 20;
    char* ws = (char*)d_ws;
    bf16* wqkv_bf = (bf16*)(ws);
    bf16* wout_bf = (bf16*)(ws + 6 * MB);
    bf16* w1_bf   = (bf16*)(ws);
    bf16* w2_bf   = (bf16*)(ws + 8 * MB);
    bf16* qkv     = (bf16*)(ws + 16 * MB);
    bf16* h1      = (bf16*)(ws + 16 * MB);
    bf16* hbuf    = (bf16*)(ws + 48 * MB);   // h, then o, then xn
    float* x1     = (float*)d_out;

    const dim3 blk(256);

    // Phase A: [weights Wqkv+Wout convert | LN1] fused in one launch (independent)
    {
        const int n0 = 3 * DD * DD / 8, n1 = DD * DD / 8;
        const int ncb = (n0 + n1) / 256;
        conv2ln_kernel<<<ncb + NTOK, blk, 0, stream>>>(
            Wqkv, wqkv_bf, n0, Wout, wout_bf, n1, ncb, x, ln1g, ln1b, hbuf);
    }
    // qkv = h @ Wqkv^T + bqkv           (M=4096, N=3072, K=1024; 768 blocks)
    gemm_glds<128, 0, 0, 0><<<dim3(24, 32), blk, 0, stream>>>(
        hbuf, wqkv_bf, bqkv, nullptr, qkv, 3 * DD, DD);
    // o = attention(qkv)  (o overwrites h — h dead)
    attn_kernel<<<BB * HH * (SS / 16) / 4, blk, 0, stream>>>(qkv, hbuf);
    // x1 = x + o @ Wout^T + bout        (fp32 into d_out; M=4096, N=1024, K=1024)
    gemm_glds<64, 0, 2, 1><<<dim3(8, 64), blk, 0, stream>>>(
        hbuf, wout_bf, bout, x, x1, DD, DD);

    // Phase B: [weights W1+W2 convert | LN2] fused (both legal only after out-proj:
    // conv overwrites phase-A W region; LN2 reads x1)
    {
        const int n0 = DFFD * DD / 8, n1 = DFFD * DD / 8;
        const int ncb = (n0 + n1) / 256;
        conv2ln_kernel<<<ncb + NTOK, blk, 0, stream>>>(
            W1, w1_bf, n0, W2, w2_bf, n1, ncb, x1, ln2g, ln2b, hbuf);
    }
    // h1 = gelu(xn @ W1^T + b1)         (M=4096, N=4096, K=1024; 1024 blocks)
    gemm_glds<128, 1, 0, 0><<<dim3(32, 32), blk, 0, stream>>>(
        hbuf, w1_bf, b1, nullptr, h1, DFFD, DD);
    // out = x1 + h1 @ W2^T + b2         (split-K=2, TM=128: 512 blocks;
    //   8.4M atomics into pre-primed x1 in d_out)
    gemm_glds<128, 0, 3, 1><<<dim3(8, 32, 2), blk, 0, stream>>>(
        h1, w2_bf, b2, nullptr, x1, DD, DFFD);
}

// Round 12
// 288.081 us; speedup vs baseline: 1.0971x; 1.0359x over previous
//
#include <hip/hip_runtime.h>
#include <hip/hip_bf16.h>
#include <cmath>

typedef __bf16 bf16;
typedef __bf16 bf16x4 __attribute__((ext_vector_type(4)));
typedef __bf16 bf16x8 __attribute__((ext_vector_type(8)));
typedef float f32x4 __attribute__((ext_vector_type(4)));

#define BB 2
#define SS 2048
#define DD 1024
#define HH 16
#define WW 16
#define HDD 64
#define DFFD 4096
#define NTOK (BB*SS)

// gelu(x) = x * sigmoid(2*sqrt(2/pi)*(x+0.044715x^3))  == tanh-approx gelu
__device__ __forceinline__ float gelu_f(float x) {
    const float k = 1.5957691216057308f;  // 2*sqrt(2/pi)
    float u = k * (x + 0.044715f * x * x * x);
    return x / (1.0f + __expf(-u));
}

// ---- async global->LDS 16B/lane. LDS dest = wave-uniform base; HW adds lane*16. ----
__device__ __forceinline__ void glds16(const bf16* g, const bf16* l) {
    __builtin_amdgcn_global_load_lds(
        (const __attribute__((address_space(1))) void*)(uintptr_t)(const void*)g,
        (__attribute__((address_space(3))) void*)(unsigned)(uintptr_t)(const void*)l,
        16, 0, 0);
}

// ======== fused: fp32->bf16 weight convert (2 sources) + LayerNorm, one launch ========
__global__ __launch_bounds__(256) void conv2ln_kernel(
    const float* __restrict__ s0, bf16* __restrict__ d0, int n0,
    const float* __restrict__ s1, bf16* __restrict__ d1, int n1, int ncb,
    const float* __restrict__ xin, const float* __restrict__ g,
    const float* __restrict__ b, bf16* __restrict__ lnout)
{
    const int t = threadIdx.x;
    if ((int)blockIdx.x < ncb) {
        int i = blockIdx.x * 256 + t;
        const float* src; bf16* dst; int idx;
        if (i < n0) { src = s0; dst = d0; idx = i; }
        else        { idx = i - n0; if (idx >= n1) return; src = s1; dst = d1; }
        f32x4 a = *(const f32x4*)(src + (size_t)idx * 8);
        f32x4 c = *(const f32x4*)(src + (size_t)idx * 8 + 4);
        bf16x8 v;
#pragma unroll
        for (int j = 0; j < 4; j++) { v[j] = (bf16)a[j]; v[4 + j] = (bf16)c[j]; }
        *(bf16x8*)(dst + (size_t)idx * 8) = v;
        return;
    }
    // ---- LN path ----
    const int row = blockIdx.x - ncb;
    f32x4 v = *(const f32x4*)(xin + (size_t)row * DD + t * 4);
    float s  = v[0] + v[1] + v[2] + v[3];
    float s2 = v[0]*v[0] + v[1]*v[1] + v[2]*v[2] + v[3]*v[3];
#pragma unroll
    for (int off = 32; off >= 1; off >>= 1) {
        s  += __shfl_xor(s,  off, 64);
        s2 += __shfl_xor(s2, off, 64);
    }
    __shared__ float red[8];
    const int wave = t >> 6;
    if ((t & 63) == 0) { red[wave] = s; red[4 + wave] = s2; }
    __syncthreads();
    float ts  = red[0] + red[1] + red[2] + red[3];
    float ts2 = red[4] + red[5] + red[6] + red[7];
    float mean = ts * (1.0f / DD);
    float var  = ts2 * (1.0f / DD) - mean * mean;
    float rstd = rsqrtf(var + 1e-5f);
    f32x4 gv = *(const f32x4*)(g + t * 4);
    f32x4 bv = *(const f32x4*)(b + t * 4);
    bf16x4 o;
#pragma unroll
    for (int i = 0; i < 4; i++) o[i] = (bf16)((v[i] - mean) * rstd * gv[i] + bv[i]);
    *(bf16x4*)(lnout + (size_t)row * DD + t * 4) = o;
}

// ======== bf16 MFMA GEMM: ring-3 counted-vmcnt pipeline + T1 XCD swizzle ========
// C[M,N] = A[M,K] @ W[N,K]^T + bias.  256 thr. BN=128, BK=32.
// TM=256 (R11, fat wave): waves 2x2, wave tile 128x64, MI=8 x NJ=4 = 32 MFMA per
//   12 ds_read_b128 (2.67 MFMA/read vs 2.0 at TM=128) — amortizes the measured
//   ~400cyc/iter barrier+issue overhead over 2x work and makes the MFMA pipe the
//   largest per-iter component (1242 vs 1152 LDS cyc per CU-iter). LDS ring-3 =
//   72 KB -> 2 blocks/CU; __launch_bounds__(256,2) caps VGPR at 256 (acc=128).
// TM=128: waves 2x2, 4x4. TM=64: waves 1x4, 4x2.
// k-loop (R7/R9, measured floor ~1200cyc/iter at TM=128): iter t: vmcnt(L) ->
//   s_barrier -> stage(t+2) -> ds_read frags -> MFMA (no explicit lgkm drain;
//   compiler emits fine-grained waits). Ring-3 depth-2 (R10: depth-3 = parity).
//   WAR: stage(t+2) overwrites slot (t-1)%3 whose reads were consumed before
//   iter t-1's MFMAs, hence before all waves crossed barrier(t).
// T1 XCD swizzle (R8, FETCH 135.8->49.2 MB): swz=(bid&7)*cpx+(bid>>3), nbxy%8==0.
// T2 swizzle (R4, 0 conflicts): source col-group qsw=(t&3)^((srow>>1)&3) pre-inverts
//   ((row>>1)&3 is chunk-invariant since chunks are 64-row); read slot rsl.
// RESID: 2=add fp32 resid (may alias Cout, same elem same thread). 3=split-K over
// gridDim.z, unsafeAtomicAdd into pre-primed fp32 Cout, bias at z==0. ACT: 1=gelu.
template<int TM, int ACT, int RESID, int OUTF32>
__global__ __launch_bounds__(256, 2) void gemm_glds(
    const bf16* __restrict__ A, const bf16* __restrict__ Bw,
    const float* __restrict__ bias,
    const float* resid, void* __restrict__ Cout, int N, int K)
{
    constexpr int MI  = (TM == 256) ? 8 : 4;
    constexpr int NJ  = (TM == 64) ? 2 : 4;
    constexpr int ACH = TM / 64;            // A stage chunks (64 rows each)
    __shared__ __align__(16) bf16 As[3 * TM * 32];
    __shared__ __align__(16) bf16 Bs[3 * 128 * 32];
    const int t = threadIdx.x;
    // T1: bijective XCD swizzle over linearized xy grid
    const int nbxy = gridDim.x * gridDim.y;
    const int bid  = blockIdx.y * gridDim.x + blockIdx.x;
    const int cpx  = nbxy >> 3;
    const int swz  = (bid & 7) * cpx + (bid >> 3);
    const int m0 = (swz / gridDim.x) * TM;
    const int n0 = (swz % gridDim.x) * 128;
    const int lane = t & 63, w = t >> 6;
    const int wm = (TM == 256) ? (w & 1) * 128 : (TM == 128) ? (w & 1) * 64 : 0;
    const int wn = (TM == 64) ? w * 32 : (w >> 1) * 64;
    const int quad = lane >> 4, l16 = lane & 15;
    const int srow = t >> 2;                       // 4 lanes/row, 16 B each
    const int qsw  = (t & 3) ^ ((srow >> 1) & 3);  // T2 inverse perm on global source

    const bf16* Ag = A  + (size_t)(m0 + srow) * K + qsw * 8;
    const bf16* Bg = Bw + (size_t)(n0 + srow) * K + qsw * 8;

    int k_lo = 0, k_hi = K;
    if (RESID == 3) {                 // split-K: this block handles one K-slice
        const int ks = K / gridDim.z;
        k_lo = blockIdx.z * ks;
        k_hi = k_lo + ks;
    }

    auto stage = [&](int buf, int k0) {
        const bf16* AsW = As + buf * (TM * 32) + w * 512;
        const bf16* BsW = Bs + buf * (128 * 32) + w * 512;
#pragma unroll
        for (int c = 0; c < ACH; c++)
            glds16(Ag + (size_t)(c * 64) * K + k0, AsW + c * 2048);
        glds16(Bg + k0, BsW);
        glds16(Bg + (size_t)64 * K + k0, BsW + 2048);
    };

    const f32x4 zero = {0.f, 0.f, 0.f, 0.f};
    f32x4 acc[MI][NJ];
#pragma unroll
    for (int i = 0; i < MI; i++)
#pragma unroll
        for (int j = 0; j < NJ; j++) acc[i][j] = zero;

    const int nsteps = (k_hi - k_lo) >> 5;
    stage(0, k_lo);
    if (nsteps > 1) stage(1, k_lo + 32);

    const int rsl = (quad ^ ((l16 >> 1) & 3)) * 8;   // T2 read-side slot (bf16 off)
    int cur = 0, nxt2 = 2;                            // step%3, (step+2)%3
    for (int step = 0; step < nsteps; ++step) {
        // counted vmcnt: tile t+1's (ACH+2) loads may stay in flight; tile t landed.
        if (step < nsteps - 1) {
            if constexpr (TM == 256)      asm volatile("s_waitcnt vmcnt(6)" ::: "memory");
            else if constexpr (TM == 128) asm volatile("s_waitcnt vmcnt(4)" ::: "memory");
            else                          asm volatile("s_waitcnt vmcnt(3)" ::: "memory");
        } else {
            asm volatile("s_waitcnt vmcnt(0)" ::: "memory");
        }
        __builtin_amdgcn_s_barrier();
        if (step + 2 < nsteps) stage(nxt2, k_lo + ((step + 2) << 5));
        const bf16* Ab = As + cur * (TM * 32);
        const bf16* Bb = Bs + cur * (128 * 32);
        bf16x8 af[MI], bfr[NJ];
#pragma unroll
        for (int i = 0; i < MI; i++)
            af[i] = *(const bf16x8*)(Ab + (wm + i * 16 + l16) * 32 + rsl);
#pragma unroll
        for (int j = 0; j < NJ; j++)
            bfr[j] = *(const bf16x8*)(Bb + (wn + j * 16 + l16) * 32 + rsl);
        // compiler emits fine-grained lgkm waits; first MFMAs overlap ds_read latency
#pragma unroll
        for (int i = 0; i < MI; i++)
#pragma unroll
            for (int j = 0; j < NJ; j++)
                acc[i][j] = __builtin_amdgcn_mfma_f32_16x16x32_bf16(af[i], bfr[j], acc[i][j], 0, 0, 0);
        cur  = (cur  + 1 == 3) ? 0 : cur  + 1;
        nxt2 = (nxt2 + 1 == 3) ? 0 : nxt2 + 1;
    }

#pragma unroll
    for (int i = 0; i < MI; i++) {
#pragma unroll
        for (int j = 0; j < NJ; j++) {
            int col = n0 + wn + j * 16 + l16;
            float bv = bias[col];
            if (RESID == 3 && blockIdx.z != 0) bv = 0.0f;
#pragma unroll
            for (int r = 0; r < 4; r++) {
                int row = m0 + wm + i * 16 + quad * 4 + r;
                float val = acc[i][j][r] + bv;
                if (ACT == 1) val = gelu_f(val);
                size_t idx = (size_t)row * N + col;
                if (RESID == 2) val += resid[idx];
                if (RESID == 3) {
                    unsafeAtomicAdd(&((float*)Cout)[idx], val);   // HW global_atomic_add_f32
                } else if (OUTF32) {
                    ((float*)Cout)[idx] = val;
                } else {
                    ((bf16*)Cout)[idx] = (bf16)val;
                }
            }
        }
    }
}

// ---------------- Sliding-window causal attention, MFMA-tiled ----------------
// One wave per (b, h, 16-query block); window W=16 -> two 16-key tiles.
__global__ __launch_bounds__(256) void attn_kernel(
    const bf16* __restrict__ qkv, bf16* __restrict__ o)
{
    __shared__ __align__(16) bf16 Vlds[4][32 * 64];
    __shared__ __align__(16) bf16 Plds[4][16 * 32];
    const int t = threadIdx.x;
    const int w = t >> 6, lane = t & 63;
    const int quad = lane >> 4, l16 = lane & 15;
    const int gw = blockIdx.x * 4 + w;
    const int qb = gw & 127;
    const int h  = (gw >> 7) & (HH - 1);
    const int b  = gw >> 11;
    const int q0 = qb << 4;
    const size_t rs = 3 * DD;
    const bf16* Qb = qkv + (size_t)b * SS * rs + h * HDD;
    const bf16* Kb = Qb + DD;
    const bf16* Vb = Qb + 2 * DD;
    bf16* Vw = Vlds[w];
    bf16* Pw = Plds[w];

    {
        const int sub = lane >> 3;
        const int dc  = (lane & 7) * 8;
#pragma unroll
        for (int c = 0; c < 4; c++) {
            int key = q0 - 16 + c * 8 + sub;
            if (key < 0) key = 0;
            glds16(Vb + (size_t)key * rs + dc, Vw + c * 512);
        }
    }

    const int qrow = q0 + l16;
    int kr0 = q0 - 16 + l16; if (kr0 < 0) kr0 = 0;
    bf16x8 qf0  = *(const bf16x8*)(Qb + (size_t)qrow * rs + quad * 8);
    bf16x8 qf1  = *(const bf16x8*)(Qb + (size_t)qrow * rs + 32 + quad * 8);
    bf16x8 kf0a = *(const bf16x8*)(Kb + (size_t)kr0  * rs + quad * 8);
    bf16x8 kf0b = *(const bf16x8*)(Kb + (size_t)kr0  * rs + 32 + quad * 8);
    bf16x8 kf1a = *(const bf16x8*)(Kb + (size_t)qrow * rs + quad * 8);
    bf16x8 kf1b = *(const bf16x8*)(Kb + (size_t)qrow * rs + 32 + quad * 8);

    const f32x4 zero = {0.f, 0.f, 0.f, 0.f};
    f32x4 acc0 = __builtin_amdgcn_mfma_f32_16x16x32_bf16(qf0, kf0a, zero, 0, 0, 0);
    acc0 = __builtin_amdgcn_mfma_f32_16x16x32_bf16(qf1, kf0b, acc0, 0, 0, 0);
    f32x4 acc1 = __builtin_amdgcn_mfma_f32_16x16x32_bf16(qf0, kf1a, zero, 0, 0, 0);
    acc1 = __builtin_amdgcn_mfma_f32_16x16x32_bf16(qf1, kf1b, acc1, 0, 0, 0);

    float rl[4];
#pragma unroll
    for (int r = 0; r < 4; r++) {
        const int row = quad * 4 + r;
        float s0 = (l16 > row && q0 - 16 + l16 >= 0) ? acc0[r] * 0.125f : -1e30f;
        float s1 = (l16 <= row)                      ? acc1[r] * 0.125f : -1e30f;
        float m = fmaxf(s0, s1);
        m = fmaxf(m, __shfl_xor(m, 1, 64));
        m = fmaxf(m, __shfl_xor(m, 2, 64));
        m = fmaxf(m, __shfl_xor(m, 4, 64));
        m = fmaxf(m, __shfl_xor(m, 8, 64));
        float e0 = __expf(s0 - m), e1 = __expf(s1 - m);
        float sum = e0 + e1;
        sum += __shfl_xor(sum, 1, 64);
        sum += __shfl_xor(sum, 2, 64);
        sum += __shfl_xor(sum, 4, 64);
        sum += __shfl_xor(sum, 8, 64);
        rl[r] = 1.0f / sum;
        Pw[row * 32 + l16]      = (bf16)e0;
        Pw[row * 32 + 16 + l16] = (bf16)e1;
    }

    asm volatile("s_waitcnt vmcnt(0)" ::: "memory");
    bf16x8 pf = *(const bf16x8*)(Pw + l16 * 32 + quad * 8);
#pragma unroll
    for (int dt = 0; dt < 4; dt++) {
        bf16x8 vf;
#pragma unroll
        for (int jj = 0; jj < 8; jj++)
            vf[jj] = Vw[(quad * 8 + jj) * 64 + dt * 16 + l16];
        f32x4 ov = __builtin_amdgcn_mfma_f32_16x16x32_bf16(pf, vf, zero, 0, 0, 0);
#pragma unroll
        for (int r = 0; r < 4; r++) {
            const int row = quad * 4 + r;
            o[(size_t)(b * SS + q0 + row) * DD + h * HDD + dt * 16 + l16] =
                (bf16)(ov[r] * rl[r]);
        }
    }
}

// ---------------- launch ----------------
extern "C" void kernel_launch(void* const* d_in, const int* in_sizes, int n_in,
                              void* d_out, int out_size, void* d_ws, size_t ws_size,
                              hipStream_t stream)
{
    (void)in_sizes; (void)n_in; (void)out_size; (void)ws_size;
    const float* x    = (const float*)d_in[0];
    const float* ln1g = (const float*)d_in[1];
    const float* ln1b = (const float*)d_in[2];
    const float* Wqkv = (const float*)d_in[3];
    const float* bqkv = (const float*)d_in[4];
    const float* Wout = (const float*)d_in[5];
    const float* bout = (const float*)d_in[6];
    const float* ln2g = (const float*)d_in[7];
    const float* ln2b = (const float*)d_in[8];
    const float* W1   = (const float*)d_in[9];
    const float* b1   = (const float*)d_in[10];
    const float* W2   = (const float*)d_in[11];
    const float* b2   = (const float*)d_in[12];

    // Workspace (56 MiB peak):
    //   [0,16M)  W region. Phase A: Wqkv_bf @0..6M, Wout_bf @6..8M.
    //            Phase B: W1_bf @0..8M, W2_bf @8..16M (conv after out-proj).
    //   [16,48M) P region. Phase A: qkv bf16 24 MiB. Phase B: h1 bf16 32 MiB.
    //   [48,56M) H region: h (LN1 out) -> o (attn out) -> xn (LN2 out), serially.
    //   x1 fp32 lives in d_out; MLP2 split-K atomically accumulates in place.
    const size_t MB = (size_t)1 << 20;
    char* ws = (char*)d_ws;
    bf16* wqkv_bf = (bf16*)(ws);
    bf16* wout_bf = (bf16*)(ws + 6 * MB);
    bf16* w1_bf   = (bf16*)(ws);
    bf16* w2_bf   = (bf16*)(ws + 8 * MB);
    bf16* qkv     = (bf16*)(ws + 16 * MB);
    bf16* h1      = (bf16*)(ws + 16 * MB);
    bf16* hbuf    = (bf16*)(ws + 48 * MB);   // h, then o, then xn
    float* x1     = (float*)d_out;

    const dim3 blk(256);

    // Phase A: [weights Wqkv+Wout convert | LN1] fused in one launch (independent)
    {
        const int n0 = 3 * DD * DD / 8, n1 = DD * DD / 8;
        const int ncb = (n0 + n1) / 256;
        conv2ln_kernel<<<ncb + NTOK, blk, 0, stream>>>(
            Wqkv, wqkv_bf, n0, Wout, wout_bf, n1, ncb, x, ln1g, ln1b, hbuf);
    }
    // qkv = h @ Wqkv^T + bqkv           (M=4096, N=3072, K=1024; 768 blocks = 3/CU)
    gemm_glds<128, 0, 0, 0><<<dim3(24, 32), blk, 0, stream>>>(
        hbuf, wqkv_bf, bqkv, nullptr, qkv, 3 * DD, DD);
    // o = attention(qkv)  (o overwrites h — h dead)
    attn_kernel<<<BB * HH * (SS / 16) / 4, blk, 0, stream>>>(qkv, hbuf);
    // x1 = x + o @ Wout^T + bout        (fp32 into d_out; M=4096, N=1024, K=1024)
    gemm_glds<64, 0, 2, 1><<<dim3(8, 64), blk, 0, stream>>>(
        hbuf, wout_bf, bout, x, x1, DD, DD);

    // Phase B: [weights W1+W2 convert | LN2] fused (legal only after out-proj)
    {
        const int n0 = DFFD * DD / 8, n1 = DFFD * DD / 8;
        const int ncb = (n0 + n1) / 256;
        conv2ln_kernel<<<ncb + NTOK, blk, 0, stream>>>(
            W1, w1_bf, n0, W2, w2_bf, n1, ncb, x1, ln2g, ln2b, hbuf);
    }
    // h1 = gelu(xn @ W1^T + b1)         (M=4096, N=4096, K=1024; TM=256 fat wave:
    //   32x16 = 512 blocks = exactly 2/CU, 32 MFMA per 12 ds_read per wave-iter)
    gemm_glds<256, 1, 0, 0><<<dim3(32, 16), blk, 0, stream>>>(
        hbuf, w1_bf, b1, nullptr, h1, DFFD, DD);
    // out = x1 + h1 @ W2^T + b2         (split-K=2, TM=128: 512 blocks = 2/CU;
    //   8.4M atomics into pre-primed x1 in d_out)
    gemm_glds<128, 0, 3, 1><<<dim3(8, 32, 2), blk, 0, stream>>>(
        h1, w2_bf, b2, nullptr, x1, DD, DFFD);
}